// Round 10
// baseline (611.507 us; speedup 1.0000x reference)
//
#include <hip/hip_runtime.h>
#include <math.h>

#define NB 8192
#define ND 2048
#define NT 4

using bf16x8 = __attribute__((ext_vector_type(8))) short;
using f32x4  = __attribute__((ext_vector_type(4))) float;

__device__ inline unsigned short f2bf(float f) {
  unsigned int u = __float_as_uint(f);
  u += 0x7FFFu + ((u >> 16) & 1u);           // RNE
  return (unsigned short)(u >> 16);
}
__device__ inline void unpack8(uint4 u, float* f) {
  f[0] = __uint_as_float(u.x << 16); f[1] = __uint_as_float(u.x & 0xFFFF0000u);
  f[2] = __uint_as_float(u.y << 16); f[3] = __uint_as_float(u.y & 0xFFFF0000u);
  f[4] = __uint_as_float(u.z << 16); f[5] = __uint_as_float(u.z & 0xFFFF0000u);
  f[6] = __uint_as_float(u.w << 16); f[7] = __uint_as_float(u.w & 0xFFFF0000u);
}

#define GL2LDS(g, l) __builtin_amdgcn_global_load_lds( \
    (const __attribute__((address_space(1))) void*)(g), \
    (__attribute__((address_space(3))) void*)(l), 16, 0, 0)

__device__ inline void waitv0() { asm volatile("s_waitcnt vmcnt(0)" ::: "memory"); }

// LDS bijection (per 32-k subtile, 16B chunks): slot s <-> (r=s>>2, c=(s&3)^((r>>1)&3))
// -> 8 consecutive lanes of a ds_read_b128 hit 8 distinct slot%8 groups:
// conflict-free (verified SQ_LDS_BANK_CONFLICT==0, r4-r9). Writes linear via
// global_load_lds; permutation applied to the GLOBAL source address (m173).

// ---------- merged weight prep: z=0 transpose wq, z=1 transpose wk, z=2 cast wv
__global__ __launch_bounds__(256) void prep_weights(
    const float* __restrict__ wq, const float* __restrict__ wk,
    const float* __restrict__ wv, unsigned short* __restrict__ WqT,
    unsigned short* __restrict__ WkT, unsigned short* __restrict__ WvBf)
{
  __shared__ float tile[64][65];
  const int t = threadIdx.x, r = t >> 2, c0 = (t & 3) * 16;
  const int bx = blockIdx.x * 64, by = blockIdx.y * 64;
  const int z = blockIdx.z;
  if (z == 2) {
    const float* src = wv + (size_t)(by + r) * ND + bx + c0;
    unsigned short* dst = WvBf + (size_t)(by + r) * ND + bx + c0;
    float4 v0 = *reinterpret_cast<const float4*>(src);
    float4 v1 = *reinterpret_cast<const float4*>(src + 4);
    float4 v2 = *reinterpret_cast<const float4*>(src + 8);
    float4 v3 = *reinterpret_cast<const float4*>(src + 12);
    unsigned int pk[8];
    pk[0] = f2bf(v0.x) | ((unsigned)f2bf(v0.y) << 16);
    pk[1] = f2bf(v0.z) | ((unsigned)f2bf(v0.w) << 16);
    pk[2] = f2bf(v1.x) | ((unsigned)f2bf(v1.y) << 16);
    pk[3] = f2bf(v1.z) | ((unsigned)f2bf(v1.w) << 16);
    pk[4] = f2bf(v2.x) | ((unsigned)f2bf(v2.y) << 16);
    pk[5] = f2bf(v2.z) | ((unsigned)f2bf(v2.w) << 16);
    pk[6] = f2bf(v3.x) | ((unsigned)f2bf(v3.y) << 16);
    pk[7] = f2bf(v3.z) | ((unsigned)f2bf(v3.w) << 16);
    *reinterpret_cast<uint4*>(dst)     = make_uint4(pk[0], pk[1], pk[2], pk[3]);
    *reinterpret_cast<uint4*>(dst + 8) = make_uint4(pk[4], pk[5], pk[6], pk[7]);
    return;
  }
  const float* W = (z == 0) ? wq : wk;
  unsigned short* WT = (z == 0) ? WqT : WkT;
  const float* src = W + (size_t)(by + r) * ND + bx + c0;
#pragma unroll
  for (int j = 0; j < 4; ++j) {
    float4 v = *reinterpret_cast<const float4*>(src + j * 4);
    tile[r][c0 + j*4 + 0] = v.x; tile[r][c0 + j*4 + 1] = v.y;
    tile[r][c0 + j*4 + 2] = v.z; tile[r][c0 + j*4 + 3] = v.w;
  }
  __syncthreads();
  unsigned int pk[8];
#pragma unroll
  for (int j = 0; j < 8; ++j) {
    unsigned int lo = f2bf(tile[c0 + 2*j    ][r]);
    unsigned int hi = f2bf(tile[c0 + 2*j + 1][r]);
    pk[j] = lo | (hi << 16);
  }
  unsigned short* dst = WT + (size_t)(bx + r) * ND + by + c0;
  *reinterpret_cast<uint4*>(dst)     = make_uint4(pk[0], pk[1], pk[2], pk[3]);
  *reinterpret_cast<uint4*>(dst + 8) = make_uint4(pk[4], pk[5], pk[6], pk[7]);
}

// ---------- tokens + mask + LayerNorm -> F chunk (bf16) -----------------------
__global__ __launch_bounds__(256) void prep_tokens(
    const float* __restrict__ x_start, const int* __restrict__ tarr,
    const float* __restrict__ noise, const float* __restrict__ cond_src,
    const float* __restrict__ cond_tgt, const float* __restrict__ sqrt_ac,
    const float* __restrict__ sqrt_omac, unsigned short* __restrict__ F,
    float* __restrict__ maskf, int b0)
{
  const int cb = blockIdx.y, tok = blockIdx.x, tid = threadIdx.x;
  const int b = b0 + cb;
  const int e0 = tid * 8;
  float v[8];
  if (tok == 0) {
    const int tb = tarr[b];
    const float sa = sqrt_ac[tb], so = sqrt_omac[tb];
    const float4* xs = reinterpret_cast<const float4*>(x_start + (size_t)b * ND + e0);
    const float4* ns = reinterpret_cast<const float4*>(noise + (size_t)b * ND + e0);
    float4 x0 = xs[0], x1 = xs[1], n0 = ns[0], n1 = ns[1];
    v[0] = sa*x0.x + so*n0.x; v[1] = sa*x0.y + so*n0.y;
    v[2] = sa*x0.z + so*n0.z; v[3] = sa*x0.w + so*n0.w;
    v[4] = sa*x1.x + so*n1.x; v[5] = sa*x1.y + so*n1.y;
    v[6] = sa*x1.z + so*n1.z; v[7] = sa*x1.w + so*n1.w;
  } else if (tok == 1) {
    const float tf = (float)tarr[b];
    const float cc = -9.210340371976184f / 1023.0f;  // -ln(10000)/(half-1)
#pragma unroll
    for (int j = 0; j < 8; ++j) {
      int e = e0 + j;
      int i = (e < 1024) ? e : (e - 1024);
      float a = tf * expf((float)i * cc);
      v[j] = (e < 1024) ? sinf(a) : cosf(a);
    }
  } else {
    const float* src = (tok == 2) ? cond_src : cond_tgt;
    const float4* ps = reinterpret_cast<const float4*>(src + (size_t)b * ND + e0);
    float4 a0 = ps[0], a1 = ps[1];
    v[0]=a0.x; v[1]=a0.y; v[2]=a0.z; v[3]=a0.w;
    v[4]=a1.x; v[5]=a1.y; v[6]=a1.z; v[7]=a1.w;
  }
  float s = 0.f, s2 = 0.f, sab = 0.f;
#pragma unroll
  for (int j = 0; j < 8; ++j) { s += v[j]; s2 += v[j]*v[j]; sab += fabsf(v[j]); }
#pragma unroll
  for (int o = 32; o > 0; o >>= 1) {
    s += __shfl_xor(s, o); s2 += __shfl_xor(s2, o); sab += __shfl_xor(sab, o);
  }
  __shared__ float red[12];
  const int lane = tid & 63, wid = tid >> 6;
  if (lane == 0) { red[wid*3+0] = s; red[wid*3+1] = s2; red[wid*3+2] = sab; }
  __syncthreads();
  s   = red[0] + red[3] + red[6] + red[9];
  s2  = red[1] + red[4] + red[7] + red[10];
  sab = red[2] + red[5] + red[8] + red[11];
  const float mu  = s * (1.0f / ND);
  const float var = s2 * (1.0f / ND) - mu * mu;
  const float rs  = rsqrtf(var + 1e-5f);
  if (tid == 0) maskf[(size_t)cb*NT + tok] = (sab > 0.0f) ? 1.0f : 0.0f;
  unsigned int pk[4];
#pragma unroll
  for (int j = 0; j < 4; ++j) {
    unsigned int lo = f2bf((v[2*j]   - mu) * rs);
    unsigned int hi = f2bf((v[2*j+1] - mu) * rs);
    pk[j] = lo | (hi << 16);
  }
  *reinterpret_cast<uint4*>(F + ((size_t)cb*NT + tok) * ND + e0) =
      make_uint4(pk[0], pk[1], pk[2], pk[3]);
}

// ---------- 128^2 GEMM core (swizzled LDS): C=A*B^T, bf16 out (G-GEMM) --------
__global__ __launch_bounds__(256) void gemm_nt_bf16(
    const unsigned short* __restrict__ A, const unsigned short* __restrict__ B,
    unsigned short* __restrict__ C)
{
  constexpr int K = ND;
  __shared__ unsigned short As[128*32];
  __shared__ unsigned short Bs[128*32];
  const int tid = threadIdx.x;
  const int lane = tid & 63, wid = tid >> 6;
  const int wm = wid >> 1, wn = wid & 1;
  const size_t arow0 = (size_t)blockIdx.y * 128;
  const size_t bcol0 = (size_t)blockIdx.x * 128;
  f32x4 acc[4][4] = {};
  const int row0 = tid >> 2, row1 = row0 + 64;
  const int kc = (((tid & 3) ^ ((tid >> 3) & 3))) * 8;
  const unsigned short* ga0 = A + (arow0 + row0) * K + kc;
  const unsigned short* ga1 = A + (arow0 + row1) * K + kc;
  const unsigned short* gb0 = B + (bcol0 + row0) * K + kc;
  const unsigned short* gb1 = B + (bcol0 + row1) * K + kc;
  char* lAs = (char*)As; char* lBs = (char*)Bs;
  const int lo0 = wid * 1024, lo1 = 4096 + wid * 1024;
  const int ar = (lane & 15);
  const int ko = ((lane >> 4) ^ ((lane >> 1) & 3)) * 8;
  for (int k0 = 0; k0 < K; k0 += 32) {
    GL2LDS(ga0 + k0, lAs + lo0);
    GL2LDS(ga1 + k0, lAs + lo1);
    GL2LDS(gb0 + k0, lBs + lo0);
    GL2LDS(gb1 + k0, lBs + lo1);
    __syncthreads();
    bf16x8 af[4], bfr[4];
#pragma unroll
    for (int mi = 0; mi < 4; ++mi)
      af[mi] = *reinterpret_cast<const bf16x8*>(&As[(wm*64 + mi*16 + ar)*32 + ko]);
#pragma unroll
    for (int ni = 0; ni < 4; ++ni)
      bfr[ni] = *reinterpret_cast<const bf16x8*>(&Bs[(wn*64 + ni*16 + ar)*32 + ko]);
#pragma unroll
    for (int mi = 0; mi < 4; ++mi)
#pragma unroll
      for (int ni = 0; ni < 4; ++ni)
        acc[mi][ni] = __builtin_amdgcn_mfma_f32_16x16x32_bf16(af[mi], bfr[ni], acc[mi][ni], 0, 0, 0);
    __syncthreads();
  }
#pragma unroll
  for (int mi = 0; mi < 4; ++mi)
#pragma unroll
    for (int ni = 0; ni < 4; ++ni) {
      const size_t col = bcol0 + wn*64 + ni*16 + (lane & 15);
#pragma unroll
      for (int r = 0; r < 4; ++r) {
        const size_t row = arow0 + wm*64 + mi*16 + (lane >> 4)*4 + r;
        C[row * ND + col] = f2bf(acc[mi][ni][r]);
      }
    }
}

// ---------- H-GEMM: 256x128 tile, BK=32, RING-2 (48 KiB), 2 blocks/CU ---------
// Fixes r9's flaw: double-buffered ring removes the serial per-tile drain
// (stage t+1 targets the opposite ring; boundary vmcnt(0) waits loads issued a
// full tile earlier). 2 co-resident blocks (acc 64 AGPR + ~60 VGPR <= 128 via
// __launch_bounds__(512,4); LDS 2x48=96 KiB) fill each other's read/barrier
// windows via CU wave co-scheduling (m114). 8 waves 4M x 2N, per-wave 64x64.
__global__ __launch_bounds__(512, 4) void gemm_hx(
    const unsigned short* __restrict__ A, const unsigned short* __restrict__ B,
    unsigned short* __restrict__ C)
{
  constexpr int K = 2048;
  constexpr int NTILE = K / 32;   // 64
  __shared__ unsigned short lds[24576];  // 48 KiB: 2 rings x (A 16K + B 8K)
  const int tid = threadIdx.x;
  const int lane = tid & 63, wid = tid >> 6;
  const int wm = wid >> 1, wn = wid & 1;   // 4M x 2N

  const int GX = (int)gridDim.x;   // 16
  const int nwg = GX * (int)gridDim.y;
  const int o = (int)blockIdx.y * GX + (int)blockIdx.x;
  const int swz = (o & 7) * (nwg >> 3) + (o >> 3);
  const int bx = swz % GX, by = swz / GX;
  const size_t arow0 = (size_t)by * 256;
  const size_t bcol0 = (size_t)bx * 128;
  char* ldsb = (char*)lds;

  // staging: A = 1024 slots (2 loads/thread), B = 512 slots (1 load/thread)
  const int rA = tid >> 2, cA = (tid & 3) ^ ((rA >> 1) & 3);
  const unsigned short* gA0 = A + (arow0 + rA) * K + cA * 8;
  const unsigned short* gA1 = A + (arow0 + rA + 128) * K + cA * 8;  // same swizzle: (rA+128) keeps (r>>1)&3
  const unsigned short* gB  = B + (bcol0 + rA) * K + cA * 8;
  const int ldsA0 = wid * 1024;
  const int ldsA1 = 8192 + wid * 1024;
  const int ldsB  = 16384 + wid * 1024;

#define STAGE(tt) { const int q_ = ((tt)&1)*24576; const int k_ = (tt)*32; \
    GL2LDS(gA0 + k_, ldsb + q_ + ldsA0);                                   \
    GL2LDS(gA1 + k_, ldsb + q_ + ldsA1);                                   \
    GL2LDS(gB  + k_, ldsb + q_ + ldsB); }

  const int lo16 = ((lane & 15) * 4 + ((lane >> 4) ^ ((lane >> 1) & 3))) * 16;
  f32x4 acc[4][4] = {};

  STAGE(0);
  waitv0();
  __builtin_amdgcn_s_barrier();

  for (int t = 0; t < NTILE; ++t) {
    const char* rg = ldsb + (t & 1) * 24576;
    bf16x8 af[4], bfr[4];
#pragma unroll
    for (int mi = 0; mi < 4; ++mi)
      af[mi] = *reinterpret_cast<const bf16x8*>(rg + wm*4096 + mi*1024 + lo16);
#pragma unroll
    for (int ni = 0; ni < 4; ++ni)
      bfr[ni] = *reinterpret_cast<const bf16x8*>(rg + 16384 + wn*4096 + ni*1024 + lo16);
    if (t + 1 < NTILE) STAGE(t + 1);
    __builtin_amdgcn_s_setprio(1);
#pragma unroll
    for (int mi = 0; mi < 4; ++mi)
#pragma unroll
      for (int ni = 0; ni < 4; ++ni)
        acc[mi][ni] = __builtin_amdgcn_mfma_f32_16x16x32_bf16(af[mi], bfr[ni], acc[mi][ni], 0, 0, 0);
    __builtin_amdgcn_s_setprio(0);
    if (t + 1 < NTILE) waitv0();   // t+1's 3 loads, issued a full tile ago
    __builtin_amdgcn_s_barrier();
  }
#undef STAGE

  // epilogue: C/D layout col=lane&15, row=(lane>>4)*4+reg
#pragma unroll
  for (int mi = 0; mi < 4; ++mi)
#pragma unroll
    for (int ni = 0; ni < 4; ++ni) {
      const size_t col = bcol0 + wn*64 + ni*16 + (lane & 15);
#pragma unroll
      for (int r = 0; r < 4; ++r) {
        const size_t row = arow0 + wm*64 + mi*16 + (lane >> 4)*4 + r;
        C[row * 2048 + col] = f2bf(acc[mi][ni][r]);
      }
    }
}

// ---------- pred GEMM: A has row stride 8192 (U aliased into H rows 4*cb) -----
#define LDA_U 8192
__global__ __launch_bounds__(256) void gemm_nt_pred(
    const unsigned short* __restrict__ A, const unsigned short* __restrict__ B,
    float* __restrict__ outp /* = out+1 */, const float* __restrict__ x_start,
    float* __restrict__ lpart, int b0)
{
  constexpr int K = ND;
  __shared__ unsigned short As[128*32];
  __shared__ unsigned short Bs[128*32];
  __shared__ float r2[4];
  const int tid = threadIdx.x;
  const int lane = tid & 63, wid = tid >> 6;
  const int wm = wid >> 1, wn = wid & 1;
  const size_t arow0 = (size_t)blockIdx.y * 128;
  const size_t bcol0 = (size_t)blockIdx.x * 128;
  f32x4 acc[4][4] = {};
  const int row0 = tid >> 2, row1 = row0 + 64;
  const int kc = (((tid & 3) ^ ((tid >> 3) & 3))) * 8;
  const unsigned short* ga0 = A + (arow0 + row0) * LDA_U + kc;
  const unsigned short* ga1 = A + (arow0 + row1) * LDA_U + kc;
  const unsigned short* gb0 = B + (bcol0 + row0) * K + kc;
  const unsigned short* gb1 = B + (bcol0 + row1) * K + kc;
  char* lAs = (char*)As; char* lBs = (char*)Bs;
  const int lo0 = wid * 1024, lo1 = 4096 + wid * 1024;
  const int ar = (lane & 15);
  const int ko = ((lane >> 4) ^ ((lane >> 1) & 3)) * 8;
  for (int k0 = 0; k0 < K; k0 += 32) {
    GL2LDS(ga0 + k0, lAs + lo0);
    GL2LDS(ga1 + k0, lAs + lo1);
    GL2LDS(gb0 + k0, lBs + lo0);
    GL2LDS(gb1 + k0, lBs + lo1);
    __syncthreads();
    bf16x8 af[4], bfr[4];
#pragma unroll
    for (int mi = 0; mi < 4; ++mi)
      af[mi] = *reinterpret_cast<const bf16x8*>(&As[(wm*64 + mi*16 + ar)*32 + ko]);
#pragma unroll
    for (int ni = 0; ni < 4; ++ni)
      bfr[ni] = *reinterpret_cast<const bf16x8*>(&Bs[(wn*64 + ni*16 + ar)*32 + ko]);
#pragma unroll
    for (int mi = 0; mi < 4; ++mi)
#pragma unroll
      for (int ni = 0; ni < 4; ++ni)
        acc[mi][ni] = __builtin_amdgcn_mfma_f32_16x16x32_bf16(af[mi], bfr[ni], acc[mi][ni], 0, 0, 0);
    __syncthreads();
  }
  float sse = 0.f;
#pragma unroll
  for (int mi = 0; mi < 4; ++mi)
#pragma unroll
    for (int ni = 0; ni < 4; ++ni) {
      const size_t col = bcol0 + wn*64 + ni*16 + (lane & 15);
#pragma unroll
      for (int r = 0; r < 4; ++r) {
        const size_t row = arow0 + wm*64 + mi*16 + (lane >> 4)*4 + r;  // chunk-local b
        const size_t gb  = (size_t)b0 + row;                           // global b
        const float p = acc[mi][ni][r];
        outp[gb * ND + col] = p;
        const float d = p - x_start[gb * ND + col];
        sse += d * d;
      }
    }
#pragma unroll
  for (int o = 32; o > 0; o >>= 1) sse += __shfl_xor(sse, o);
  if (lane == 0) r2[wid] = sse;
  __syncthreads();
  if (tid == 0) {
    const int slot = ((b0 >> 7) + (int)blockIdx.y) * 16 + (int)blockIdx.x;
    lpart[slot] = r2[0] + r2[1] + r2[2] + r2[3];
  }
}

// ---------- per-group: logits -> softmax -> U row written OVER H row 4*cb -----
__global__ __launch_bounds__(256) void attn_u(
    const unsigned short* __restrict__ F, unsigned short* __restrict__ H,
    const float* __restrict__ maskf)
{
  const int cb = blockIdx.x, tid = threadIdx.x;
  const int e0 = tid * 8, lane = tid & 63, wid = tid >> 6;
  __shared__ float red[64];
  float f[4][8], h[4][8];
#pragma unroll
  for (int i = 0; i < 4; ++i) {
    unpack8(*reinterpret_cast<const uint4*>(F + ((size_t)cb*4 + i)*ND + e0), f[i]);
    unpack8(*reinterpret_cast<const uint4*>(H + ((size_t)cb*4 + i)*ND + e0), h[i]);
  }
  float part[16];
#pragma unroll
  for (int i = 0; i < 4; ++i)
#pragma unroll
    for (int j = 0; j < 4; ++j) {
      float p = 0.f;
#pragma unroll
      for (int r = 0; r < 8; ++r) p += f[i][r] * h[j][r];
      part[i*4+j] = p;
    }
#pragma unroll
  for (int idx = 0; idx < 16; ++idx)
#pragma unroll
    for (int o = 32; o > 0; o >>= 1) part[idx] += __shfl_xor(part[idx], o);
  if (lane == 0) {
#pragma unroll
    for (int idx = 0; idx < 16; ++idx) red[wid*16 + idx] = part[idx];
  }
  __syncthreads();
  float lg[16];
#pragma unroll
  for (int idx = 0; idx < 16; ++idx)
    lg[idx] = red[idx] + red[16+idx] + red[32+idx] + red[48+idx];

  const float scale = 0.022097086912079608f;  // 2048^-0.5
  float m[4];
#pragma unroll
  for (int j = 0; j < 4; ++j) m[j] = maskf[(size_t)cb*NT + j];
  const float denom = fmaxf(m[0]+m[1]+m[2]+m[3], 1.0f);
  float c[4] = {0.f, 0.f, 0.f, 0.f};
#pragma unroll
  for (int i = 0; i < 4; ++i) {
    float x[4];
#pragma unroll
    for (int j = 0; j < 4; ++j) x[j] = (m[j] > 0.f) ? lg[i*4+j]*scale : -1e9f;
    const float mx = fmaxf(fmaxf(x[0],x[1]), fmaxf(x[2],x[3]));
    float p[4], sum = 0.f;
#pragma unroll
    for (int j = 0; j < 4; ++j) { p[j] = expf(x[j]-mx); sum += p[j]; }
    const float w = m[i] / (sum * denom);
#pragma unroll
    for (int j = 0; j < 4; ++j) c[j] += p[j] * w;
  }
  unsigned int pk[4];
#pragma unroll
  for (int jj = 0; jj < 4; ++jj) {
    float ulo = c[0]*f[0][2*jj]   + c[1]*f[1][2*jj]   + c[2]*f[2][2*jj]   + c[3]*f[3][2*jj];
    float uhi = c[0]*f[0][2*jj+1] + c[1]*f[1][2*jj+1] + c[2]*f[2][2*jj+1] + c[3]*f[3][2*jj+1];
    pk[jj] = (unsigned int)f2bf(ulo) | ((unsigned int)f2bf(uhi) << 16);
  }
  // U[cb] overwrites H row 4*cb (this block already read all 4 H rows above)
  *reinterpret_cast<uint4*>(H + (size_t)cb*4*ND + e0) = make_uint4(pk[0],pk[1],pk[2],pk[3]);
}

// ---------- deterministic loss reduce (1024 fixed slots) ----------------------
__global__ __launch_bounds__(256) void loss_final(const float* __restrict__ lpart,
                                                  float* __restrict__ out) {
  const int tid = threadIdx.x;
  float s = 0.f;
  for (int i = tid; i < 1024; i += 256) s += lpart[i];
#pragma unroll
  for (int o = 32; o > 0; o >>= 1) s += __shfl_xor(s, o);
  __shared__ float red[4];
  const int lane = tid & 63, wid = tid >> 6;
  if (lane == 0) red[wid] = s;
  __syncthreads();
  if (tid == 0) out[0] = (red[0]+red[1]+red[2]+red[3]) * (1.0f / 16777216.0f);
}

extern "C" void kernel_launch(void* const* d_in, const int* in_sizes, int n_in,
                              void* d_out, int out_size, void* d_ws, size_t ws_size,
                              hipStream_t stream) {
  const float* x_start   = (const float*)d_in[0];
  const int*   tarr      = (const int*)  d_in[1];
  const float* noise     = (const float*)d_in[2];
  const float* cond_src  = (const float*)d_in[3];
  const float* cond_tgt  = (const float*)d_in[4];
  const float* w_q       = (const float*)d_in[5];
  const float* w_k       = (const float*)d_in[6];
  const float* w_v       = (const float*)d_in[7];
  const float* sqrt_ac   = (const float*)d_in[8];
  const float* sqrt_omac = (const float*)d_in[9];
  float* out = (float*)d_out;
  char*  ws  = (char*)d_ws;

  // U aliased into H -> need(cb) = 16.8M + cb*32784 + 4K
  size_t CB;
  if      (ws_size >= 285347840ull) CB = 8192;
  else if (ws_size >= 151064576ull) CB = 4096;
  else if (ws_size >=  83922944ull) CB = 2048;
  else if (ws_size >=  50352128ull) CB = 1024;
  else return;

  const size_t offG  = 0;
  const size_t offWv = 8388608;
  const size_t offF  = 16777216;
  const size_t szF   = CB * 16384;            // 4*CB*2048*2 bytes
  const size_t offH  = offF + szF;
  const size_t offMask = offH + szF;
  const size_t offLp   = offMask + CB * 16;

  unsigned short* G    = (unsigned short*)(ws + offG);
  unsigned short* WvBf = (unsigned short*)(ws + offWv);
  unsigned short* F    = (unsigned short*)(ws + offF);
  unsigned short* H    = (unsigned short*)(ws + offH);
  float* maskC = (float*)(ws + offMask);
  float* lpart = (float*)(ws + offLp);
  // setup-phase aliases (dead before chunk 0 writes F/H)
  unsigned short* WqT = F;
  unsigned short* WkT = H;

  prep_weights<<<dim3(32, 32, 3), 256, 0, stream>>>(w_q, w_k, w_v, WqT, WkT, WvBf);
  gemm_nt_bf16<<<dim3(16, 16), 256, 0, stream>>>(WqT, WkT, G);   // G = Wq^T Wk

  const int nchunks = NB / (int)CB;
  for (int ci = 0; ci < nchunks; ++ci) {
    const int b0 = ci * (int)CB;
    prep_tokens<<<dim3(NT, (int)CB), 256, 0, stream>>>(
        x_start, tarr, noise, cond_src, cond_tgt, sqrt_ac, sqrt_omac, F, maskC, b0);
    gemm_hx<<<dim3(16, (NT*(int)CB)/256), 512, 0, stream>>>(F, G, H);  // H = F G^T
    attn_u<<<dim3((int)CB), 256, 0, stream>>>(F, H, maskC);            // U -> H rows 4*cb
    gemm_nt_pred<<<dim3(16, (int)CB / 128), 256, 0, stream>>>(
        H /* U, lda=8192 */, WvBf, out + 1, x_start, lpart, b0);       // pred = U Wv^T
  }
  loss_final<<<dim3(1), 256, 0, stream>>>(lpart, out);
}

// Round 11
// 610.339 us; speedup vs baseline: 1.0019x; 1.0019x over previous
//
#include <hip/hip_runtime.h>
#include <math.h>

#define NB 8192
#define ND 2048
#define NT 4

using bf16x8 = __attribute__((ext_vector_type(8))) short;
using f32x4  = __attribute__((ext_vector_type(4))) float;

__device__ inline unsigned short f2bf(float f) {
  unsigned int u = __float_as_uint(f);
  u += 0x7FFFu + ((u >> 16) & 1u);           // RNE
  return (unsigned short)(u >> 16);
}
__device__ inline void unpack8(uint4 u, float* f) {
  f[0] = __uint_as_float(u.x << 16); f[1] = __uint_as_float(u.x & 0xFFFF0000u);
  f[2] = __uint_as_float(u.y << 16); f[3] = __uint_as_float(u.y & 0xFFFF0000u);
  f[4] = __uint_as_float(u.z << 16); f[5] = __uint_as_float(u.z & 0xFFFF0000u);
  f[6] = __uint_as_float(u.w << 16); f[7] = __uint_as_float(u.w & 0xFFFF0000u);
}

#define GL2LDS(g, l) __builtin_amdgcn_global_load_lds( \
    (const __attribute__((address_space(1))) void*)(g), \
    (__attribute__((address_space(3))) void*)(l), 16, 0, 0)

__device__ inline void waitv8() { asm volatile("s_waitcnt vmcnt(8)" ::: "memory"); }
__device__ inline void waitv4() { asm volatile("s_waitcnt vmcnt(4)" ::: "memory"); }
__device__ inline void waitv0() { asm volatile("s_waitcnt vmcnt(0)" ::: "memory"); }

// LDS bijection (per 32-k subtile, 16B chunks): slot s <-> (r=s>>2, c=(s&3)^((r>>1)&3))
// -> 8 consecutive lanes of a ds_read_b128 hit 8 distinct slot%8 groups:
// conflict-free (verified SQ_LDS_BANK_CONFLICT==0, r4-r10). Writes linear via
// global_load_lds; permutation applied to the GLOBAL source address (m173).

// ---------- merged weight prep: z=0 transpose wq, z=1 transpose wk, z=2 cast wv
__global__ __launch_bounds__(256) void prep_weights(
    const float* __restrict__ wq, const float* __restrict__ wk,
    const float* __restrict__ wv, unsigned short* __restrict__ WqT,
    unsigned short* __restrict__ WkT, unsigned short* __restrict__ WvBf)
{
  __shared__ float tile[64][65];
  const int t = threadIdx.x, r = t >> 2, c0 = (t & 3) * 16;
  const int bx = blockIdx.x * 64, by = blockIdx.y * 64;
  const int z = blockIdx.z;
  if (z == 2) {
    const float* src = wv + (size_t)(by + r) * ND + bx + c0;
    unsigned short* dst = WvBf + (size_t)(by + r) * ND + bx + c0;
    float4 v0 = *reinterpret_cast<const float4*>(src);
    float4 v1 = *reinterpret_cast<const float4*>(src + 4);
    float4 v2 = *reinterpret_cast<const float4*>(src + 8);
    float4 v3 = *reinterpret_cast<const float4*>(src + 12);
    unsigned int pk[8];
    pk[0] = f2bf(v0.x) | ((unsigned)f2bf(v0.y) << 16);
    pk[1] = f2bf(v0.z) | ((unsigned)f2bf(v0.w) << 16);
    pk[2] = f2bf(v1.x) | ((unsigned)f2bf(v1.y) << 16);
    pk[3] = f2bf(v1.z) | ((unsigned)f2bf(v1.w) << 16);
    pk[4] = f2bf(v2.x) | ((unsigned)f2bf(v2.y) << 16);
    pk[5] = f2bf(v2.z) | ((unsigned)f2bf(v2.w) << 16);
    pk[6] = f2bf(v3.x) | ((unsigned)f2bf(v3.y) << 16);
    pk[7] = f2bf(v3.z) | ((unsigned)f2bf(v3.w) << 16);
    *reinterpret_cast<uint4*>(dst)     = make_uint4(pk[0], pk[1], pk[2], pk[3]);
    *reinterpret_cast<uint4*>(dst + 8) = make_uint4(pk[4], pk[5], pk[6], pk[7]);
    return;
  }
  const float* W = (z == 0) ? wq : wk;
  unsigned short* WT = (z == 0) ? WqT : WkT;
  const float* src = W + (size_t)(by + r) * ND + bx + c0;
#pragma unroll
  for (int j = 0; j < 4; ++j) {
    float4 v = *reinterpret_cast<const float4*>(src + j * 4);
    tile[r][c0 + j*4 + 0] = v.x; tile[r][c0 + j*4 + 1] = v.y;
    tile[r][c0 + j*4 + 2] = v.z; tile[r][c0 + j*4 + 3] = v.w;
  }
  __syncthreads();
  unsigned int pk[8];
#pragma unroll
  for (int j = 0; j < 8; ++j) {
    unsigned int lo = f2bf(tile[c0 + 2*j    ][r]);
    unsigned int hi = f2bf(tile[c0 + 2*j + 1][r]);
    pk[j] = lo | (hi << 16);
  }
  unsigned short* dst = WT + (size_t)(bx + r) * ND + by + c0;
  *reinterpret_cast<uint4*>(dst)     = make_uint4(pk[0], pk[1], pk[2], pk[3]);
  *reinterpret_cast<uint4*>(dst + 8) = make_uint4(pk[4], pk[5], pk[6], pk[7]);
}

// ---------- tokens + mask + LayerNorm -> F chunk (bf16) -----------------------
__global__ __launch_bounds__(256) void prep_tokens(
    const float* __restrict__ x_start, const int* __restrict__ tarr,
    const float* __restrict__ noise, const float* __restrict__ cond_src,
    const float* __restrict__ cond_tgt, const float* __restrict__ sqrt_ac,
    const float* __restrict__ sqrt_omac, unsigned short* __restrict__ F,
    float* __restrict__ maskf, int b0)
{
  const int cb = blockIdx.y, tok = blockIdx.x, tid = threadIdx.x;
  const int b = b0 + cb;
  const int e0 = tid * 8;
  float v[8];
  if (tok == 0) {
    const int tb = tarr[b];
    const float sa = sqrt_ac[tb], so = sqrt_omac[tb];
    const float4* xs = reinterpret_cast<const float4*>(x_start + (size_t)b * ND + e0);
    const float4* ns = reinterpret_cast<const float4*>(noise + (size_t)b * ND + e0);
    float4 x0 = xs[0], x1 = xs[1], n0 = ns[0], n1 = ns[1];
    v[0] = sa*x0.x + so*n0.x; v[1] = sa*x0.y + so*n0.y;
    v[2] = sa*x0.z + so*n0.z; v[3] = sa*x0.w + so*n0.w;
    v[4] = sa*x1.x + so*n1.x; v[5] = sa*x1.y + so*n1.y;
    v[6] = sa*x1.z + so*n1.z; v[7] = sa*x1.w + so*n1.w;
  } else if (tok == 1) {
    const float tf = (float)tarr[b];
    const float cc = -9.210340371976184f / 1023.0f;  // -ln(10000)/(half-1)
#pragma unroll
    for (int j = 0; j < 8; ++j) {
      int e = e0 + j;
      int i = (e < 1024) ? e : (e - 1024);
      float a = tf * expf((float)i * cc);
      v[j] = (e < 1024) ? sinf(a) : cosf(a);
    }
  } else {
    const float* src = (tok == 2) ? cond_src : cond_tgt;
    const float4* ps = reinterpret_cast<const float4*>(src + (size_t)b * ND + e0);
    float4 a0 = ps[0], a1 = ps[1];
    v[0]=a0.x; v[1]=a0.y; v[2]=a0.z; v[3]=a0.w;
    v[4]=a1.x; v[5]=a1.y; v[6]=a1.z; v[7]=a1.w;
  }
  float s = 0.f, s2 = 0.f, sab = 0.f;
#pragma unroll
  for (int j = 0; j < 8; ++j) { s += v[j]; s2 += v[j]*v[j]; sab += fabsf(v[j]); }
#pragma unroll
  for (int o = 32; o > 0; o >>= 1) {
    s += __shfl_xor(s, o); s2 += __shfl_xor(s2, o); sab += __shfl_xor(sab, o);
  }
  __shared__ float red[12];
  const int lane = tid & 63, wid = tid >> 6;
  if (lane == 0) { red[wid*3+0] = s; red[wid*3+1] = s2; red[wid*3+2] = sab; }
  __syncthreads();
  s   = red[0] + red[3] + red[6] + red[9];
  s2  = red[1] + red[4] + red[7] + red[10];
  sab = red[2] + red[5] + red[8] + red[11];
  const float mu  = s * (1.0f / ND);
  const float var = s2 * (1.0f / ND) - mu * mu;
  const float rs  = rsqrtf(var + 1e-5f);
  if (tid == 0) maskf[(size_t)cb*NT + tok] = (sab > 0.0f) ? 1.0f : 0.0f;
  unsigned int pk[4];
#pragma unroll
  for (int j = 0; j < 4; ++j) {
    unsigned int lo = f2bf((v[2*j]   - mu) * rs);
    unsigned int hi = f2bf((v[2*j+1] - mu) * rs);
    pk[j] = lo | (hi << 16);
  }
  *reinterpret_cast<uint4*>(F + ((size_t)cb*NT + tok) * ND + e0) =
      make_uint4(pk[0], pk[1], pk[2], pk[3]);
}

// ---------- 128^2 GEMM core (swizzled LDS): C=A*B^T, bf16 out (G-GEMM) --------
__global__ __launch_bounds__(256) void gemm_nt_bf16(
    const unsigned short* __restrict__ A, const unsigned short* __restrict__ B,
    unsigned short* __restrict__ C)
{
  constexpr int K = ND;
  __shared__ unsigned short As[128*32];
  __shared__ unsigned short Bs[128*32];
  const int tid = threadIdx.x;
  const int lane = tid & 63, wid = tid >> 6;
  const int wm = wid >> 1, wn = wid & 1;
  const size_t arow0 = (size_t)blockIdx.y * 128;
  const size_t bcol0 = (size_t)blockIdx.x * 128;
  f32x4 acc[4][4] = {};
  const int row0 = tid >> 2, row1 = row0 + 64;
  const int kc = (((tid & 3) ^ ((tid >> 3) & 3))) * 8;
  const unsigned short* ga0 = A + (arow0 + row0) * K + kc;
  const unsigned short* ga1 = A + (arow0 + row1) * K + kc;
  const unsigned short* gb0 = B + (bcol0 + row0) * K + kc;
  const unsigned short* gb1 = B + (bcol0 + row1) * K + kc;
  char* lAs = (char*)As; char* lBs = (char*)Bs;
  const int lo0 = wid * 1024, lo1 = 4096 + wid * 1024;
  const int ar = (lane & 15);
  const int ko = ((lane >> 4) ^ ((lane >> 1) & 3)) * 8;
  for (int k0 = 0; k0 < K; k0 += 32) {
    GL2LDS(ga0 + k0, lAs + lo0);
    GL2LDS(ga1 + k0, lAs + lo1);
    GL2LDS(gb0 + k0, lBs + lo0);
    GL2LDS(gb1 + k0, lBs + lo1);
    __syncthreads();
    bf16x8 af[4], bfr[4];
#pragma unroll
    for (int mi = 0; mi < 4; ++mi)
      af[mi] = *reinterpret_cast<const bf16x8*>(&As[(wm*64 + mi*16 + ar)*32 + ko]);
#pragma unroll
    for (int ni = 0; ni < 4; ++ni)
      bfr[ni] = *reinterpret_cast<const bf16x8*>(&Bs[(wn*64 + ni*16 + ar)*32 + ko]);
#pragma unroll
    for (int mi = 0; mi < 4; ++mi)
#pragma unroll
      for (int ni = 0; ni < 4; ++ni)
        acc[mi][ni] = __builtin_amdgcn_mfma_f32_16x16x32_bf16(af[mi], bfr[ni], acc[mi][ni], 0, 0, 0);
    __syncthreads();
  }
#pragma unroll
  for (int mi = 0; mi < 4; ++mi)
#pragma unroll
    for (int ni = 0; ni < 4; ++ni) {
      const size_t col = bcol0 + wn*64 + ni*16 + (lane & 15);
#pragma unroll
      for (int r = 0; r < 4; ++r) {
        const size_t row = arow0 + wm*64 + mi*16 + (lane >> 4)*4 + r;
        C[row * ND + col] = f2bf(acc[mi][ni][r]);
      }
    }
}

// ---------- H-GEMM (r7 verbatim): 256^2, BK=64, ring-2, 8-phase schedule ------
__global__ __launch_bounds__(512, 2) void gemm_nt_256(
    const unsigned short* __restrict__ A, const unsigned short* __restrict__ B,
    unsigned short* __restrict__ C)
{
  constexpr int K = 2048;
  constexpr int NTILE = K / 64;   // 32
  constexpr int NITER = NTILE / 2;
  __shared__ unsigned short lds[65536];  // 128 KiB: 2 rings x (A 32K + B 32K)
  const int tid = threadIdx.x;
  const int lane = tid & 63, wid = tid >> 6;
  const int wm = wid >> 2, wn = wid & 3;

  const int GX = (int)gridDim.x;
  const int nwg = GX * (int)gridDim.y;
  const int o = (int)blockIdx.y * GX + (int)blockIdx.x;
  const int swz = (o & 7) * (nwg >> 3) + (o >> 3);
  const int bx = swz % GX, by = swz / GX;

  const size_t arow0 = (size_t)by * 256;
  const size_t bcol0 = (size_t)bx * 256;
  char* ldsb = (char*)lds;

  const int s0w = wid*64 + lane, s1w = s0w + 512;
  const int rS0 = s0w >> 2, cS0 = (s0w & 3) ^ ((rS0 >> 1) & 3);
  const int rS1 = s1w >> 2, cS1 = (s1w & 3) ^ ((rS1 >> 1) & 3);
  const unsigned short* gA0 = A + (arow0 + rS0) * K + cS0*8;
  const unsigned short* gA1 = A + (arow0 + rS1) * K + cS1*8;
  const unsigned short* gB0 = B + (bcol0 + rS0) * K + cS0*8;
  const unsigned short* gB1 = B + (bcol0 + rS1) * K + cS1*8;
  const int ldsw0 = wid * 1024;
  const int ldsw1 = 8192 + wid * 1024;

#define STAGE_AH(tt,h) { const int q_ = ((tt)&1)*65536; const int k_ = (tt)*64 + (h)*32; \
    GL2LDS(gA0 + k_, ldsb + q_ + (h)*16384 + ldsw0);                                     \
    GL2LDS(gA1 + k_, ldsb + q_ + (h)*16384 + ldsw1); }
#define STAGE_BH(tt,h) { const int q_ = ((tt)&1)*65536; const int k_ = (tt)*64 + (h)*32; \
    GL2LDS(gB0 + k_, ldsb + q_ + 32768 + (h)*16384 + ldsw0);                             \
    GL2LDS(gB1 + k_, ldsb + q_ + 32768 + (h)*16384 + ldsw1); }

  const int lo16 = ((lane & 15) * 4 + ((lane >> 4) ^ ((lane >> 1) & 3))) * 16;

  f32x4 acc[8][4] = {};
  bf16x8 aA[4][2], bB[4][2];

#define LGKM0 { asm volatile("s_waitcnt lgkmcnt(0)" ::: "memory"); \
                __builtin_amdgcn_sched_barrier(0); }
#define BAR   __builtin_amdgcn_s_barrier()

  STAGE_AH(0,0); STAGE_AH(0,1); STAGE_BH(0,0); STAGE_BH(0,1);
  STAGE_AH(1,0); STAGE_AH(1,1); STAGE_BH(1,0); STAGE_BH(1,1);
  waitv8();
  BAR;

  for (int it = 0; it < NITER; ++it) {
    const int t0 = 2 * it;
    const bool st0 = (t0 + 2 < NTILE);
    const bool st1 = (t0 + 3 < NTILE);
#pragma unroll
    for (int half = 0; half < 2; ++half) {
      const char* rg = ldsb + half * 65536;
#pragma unroll
      for (int i = 0; i < 4; ++i)
#pragma unroll
        for (int kh = 0; kh < 2; ++kh)
          aA[i][kh] = *reinterpret_cast<const bf16x8*>(rg + kh*16384 + wm*8192 + i*1024 + lo16);
#pragma unroll
      for (int n = 0; n < 2; ++n)
#pragma unroll
        for (int kh = 0; kh < 2; ++kh)
          bB[n][kh] = *reinterpret_cast<const bf16x8*>(rg + 32768 + kh*16384 + wn*4096 + n*1024 + lo16);
      if (half == 1 && st0) { STAGE_BH(t0+2,0); STAGE_BH(t0+2,1); }
      BAR; LGKM0;
      __builtin_amdgcn_s_setprio(1);
#pragma unroll
      for (int i = 0; i < 4; ++i)
#pragma unroll
        for (int n = 0; n < 2; ++n)
#pragma unroll
          for (int kh = 0; kh < 2; ++kh)
            acc[i][n] = __builtin_amdgcn_mfma_f32_16x16x32_bf16(aA[i][kh], bB[n][kh], acc[i][n], 0, 0, 0);
      __builtin_amdgcn_s_setprio(0);
      BAR;
#pragma unroll
      for (int n = 2; n < 4; ++n)
#pragma unroll
        for (int kh = 0; kh < 2; ++kh)
          bB[n][kh] = *reinterpret_cast<const bf16x8*>(rg + 32768 + kh*16384 + wn*4096 + n*1024 + lo16);
      BAR; LGKM0;
      __builtin_amdgcn_s_setprio(1);
#pragma unroll
      for (int i = 0; i < 4; ++i)
#pragma unroll
        for (int n = 2; n < 4; ++n)
#pragma unroll
          for (int kh = 0; kh < 2; ++kh)
            acc[i][n] = __builtin_amdgcn_mfma_f32_16x16x32_bf16(aA[i][kh], bB[n][kh], acc[i][n], 0, 0, 0);
      __builtin_amdgcn_s_setprio(0);
      BAR;
#pragma unroll
      for (int i = 0; i < 4; ++i)
#pragma unroll
        for (int kh = 0; kh < 2; ++kh)
          aA[i][kh] = *reinterpret_cast<const bf16x8*>(rg + kh*16384 + wm*8192 + (i+4)*1024 + lo16);
      BAR; LGKM0;
      __builtin_amdgcn_s_setprio(1);
#pragma unroll
      for (int i = 0; i < 4; ++i)
#pragma unroll
        for (int n = 2; n < 4; ++n)
#pragma unroll
          for (int kh = 0; kh < 2; ++kh)
            acc[i+4][n] = __builtin_amdgcn_mfma_f32_16x16x32_bf16(aA[i][kh], bB[n][kh], acc[i+4][n], 0, 0, 0);
      __builtin_amdgcn_s_setprio(0);
      BAR;
      if (half == 0) { if (st0) { STAGE_AH(t0+2,0); STAGE_AH(t0+2,1); } }
      else if (st1) { STAGE_AH(t0+3,0); STAGE_AH(t0+3,1); STAGE_BH(t0+3,0); STAGE_BH(t0+3,1); }
      BAR;
      __builtin_amdgcn_s_setprio(1);
#pragma unroll
      for (int i = 0; i < 4; ++i)
#pragma unroll
        for (int n = 0; n < 2; ++n)
#pragma unroll
          for (int kh = 0; kh < 2; ++kh)
            acc[i+4][n] = __builtin_amdgcn_mfma_f32_16x16x32_bf16(aA[i][kh], bB[n][kh], acc[i+4][n], 0, 0, 0);
      __builtin_amdgcn_s_setprio(0);
      if (half == 0) { if (st0) waitv4(); else waitv0(); }
      else           { if (st1) waitv8(); else waitv0(); }
      BAR;
    }
  }
#undef STAGE_AH
#undef STAGE_BH
#undef LGKM0
#undef BAR

#pragma unroll
  for (int mi = 0; mi < 8; ++mi)
#pragma unroll
    for (int ni = 0; ni < 4; ++ni) {
      const size_t col = bcol0 + wn*64 + ni*16 + (lane & 15);
#pragma unroll
      for (int r = 0; r < 4; ++r) {
        const size_t row = arow0 + wm*128 + mi*16 + (lane >> 4)*4 + r;
        C[row * 2048 + col] = f2bf(acc[mi][ni][r]);
      }
    }
}

// ---------- pred GEMM: 128^2, BK=32, RING-2 (32 KiB), 4 blocks/CU -------------
// A = U aliased into H (row stride 8192). 4 waves (2M x 2N), 1 wave/SIMD/block;
// __launch_bounds__(256,4) + 32KB LDS -> 4 co-resident blocks/CU = 4 INDEPENDENT
// waves/SIMD (no shared barriers across blocks -> natural anti-phase; m97's
// concurrency regime). Ring-2 removes the m97 pre-barrier drain.
#define LDA_U 8192
__global__ __launch_bounds__(256, 4) void gemm_pred_r2(
    const unsigned short* __restrict__ A, const unsigned short* __restrict__ B,
    float* __restrict__ outp /* = out+1 */, const float* __restrict__ x_start,
    float* __restrict__ lpart, int b0)
{
  constexpr int K = ND;
  constexpr int NTILE = K / 32;   // 64
  __shared__ unsigned short lds[16384];  // 32 KiB: 2 rings x (A 8K + B 8K)
  __shared__ float r2[4];
  const int tid = threadIdx.x;
  const int lane = tid & 63, wid = tid >> 6;
  const int wm = wid >> 1, wn = wid & 1;

  const int GX = (int)gridDim.x;   // 16
  const int nwg = GX * (int)gridDim.y;
  const int o = (int)blockIdx.y * GX + (int)blockIdx.x;
  const int swz = (o & 7) * (nwg >> 3) + (o >> 3);
  const int bx = swz % GX, by = swz / GX;
  const size_t arow0 = (size_t)by * 128;
  const size_t bcol0 = (size_t)bx * 128;
  char* ldsb = (char*)lds;

  const int row0 = tid >> 2, row1 = row0 + 64;
  const int kc = (((tid & 3) ^ ((tid >> 3) & 3))) * 8;
  const unsigned short* ga0 = A + (arow0 + row0) * LDA_U + kc;
  const unsigned short* ga1 = A + (arow0 + row1) * LDA_U + kc;
  const unsigned short* gb0 = B + (bcol0 + row0) * K + kc;
  const unsigned short* gb1 = B + (bcol0 + row1) * K + kc;
  const int lo0 = wid * 1024, lo1 = 4096 + wid * 1024;

#define STAGE(tt) { const int q_ = ((tt)&1)*16384; const int k_ = (tt)*32; \
    GL2LDS(ga0 + k_, ldsb + q_ + lo0);                                     \
    GL2LDS(ga1 + k_, ldsb + q_ + lo1);                                     \
    GL2LDS(gb0 + k_, ldsb + q_ + 8192 + lo0);                              \
    GL2LDS(gb1 + k_, ldsb + q_ + 8192 + lo1); }

  const int ar = (lane & 15);
  const int ko2 = ((lane >> 4) ^ ((lane >> 1) & 3)) * 16;  // bytes

  f32x4 acc[4][4] = {};

  STAGE(0);
  waitv0();
  __builtin_amdgcn_s_barrier();

  for (int t = 0; t < NTILE; ++t) {
    const char* rg = ldsb + (t & 1) * 16384;
    bf16x8 af[4], bfr[4];
#pragma unroll
    for (int mi = 0; mi < 4; ++mi)
      af[mi] = *reinterpret_cast<const bf16x8*>(rg + (wm*64 + mi*16 + ar)*64 + ko2);
#pragma unroll
    for (int ni = 0; ni < 4; ++ni)
      bfr[ni] = *reinterpret_cast<const bf16x8*>(rg + 8192 + (wn*64 + ni*16 + ar)*64 + ko2);
    if (t + 1 < NTILE) STAGE(t + 1);
    __builtin_amdgcn_s_setprio(1);
#pragma unroll
    for (int mi = 0; mi < 4; ++mi)
#pragma unroll
      for (int ni = 0; ni < 4; ++ni)
        acc[mi][ni] = __builtin_amdgcn_mfma_f32_16x16x32_bf16(af[mi], bfr[ni], acc[mi][ni], 0, 0, 0);
    __builtin_amdgcn_s_setprio(0);
    if (t + 1 < NTILE) waitv0();
    __builtin_amdgcn_s_barrier();
  }
#undef STAGE

  float sse = 0.f;
#pragma unroll
  for (int mi = 0; mi < 4; ++mi)
#pragma unroll
    for (int ni = 0; ni < 4; ++ni) {
      const size_t col = bcol0 + wn*64 + ni*16 + (lane & 15);
#pragma unroll
      for (int r = 0; r < 4; ++r) {
        const size_t row = arow0 + wm*64 + mi*16 + (lane >> 4)*4 + r;  // chunk-local b
        const size_t gb  = (size_t)b0 + row;                           // global b
        const float p = acc[mi][ni][r];
        outp[gb * ND + col] = p;
        const float d = p - x_start[gb * ND + col];
        sse += d * d;
      }
    }
#pragma unroll
  for (int o2 = 32; o2 > 0; o2 >>= 1) sse += __shfl_xor(sse, o2);
  if (lane == 0) r2[wid] = sse;
  __syncthreads();
  if (tid == 0) {
    const int slot = ((b0 >> 7) + by) * 16 + bx;
    lpart[slot] = r2[0] + r2[1] + r2[2] + r2[3];
  }
}

// ---------- per-group: logits -> softmax -> U row written OVER H row 4*cb -----
__global__ __launch_bounds__(256) void attn_u(
    const unsigned short* __restrict__ F, unsigned short* __restrict__ H,
    const float* __restrict__ maskf)
{
  const int cb = blockIdx.x, tid = threadIdx.x;
  const int e0 = tid * 8, lane = tid & 63, wid = tid >> 6;
  __shared__ float red[64];
  float f[4][8], h[4][8];
#pragma unroll
  for (int i = 0; i < 4; ++i) {
    unpack8(*reinterpret_cast<const uint4*>(F + ((size_t)cb*4 + i)*ND + e0), f[i]);
    unpack8(*reinterpret_cast<const uint4*>(H + ((size_t)cb*4 + i)*ND + e0), h[i]);
  }
  float part[16];
#pragma unroll
  for (int i = 0; i < 4; ++i)
#pragma unroll
    for (int j = 0; j < 4; ++j) {
      float p = 0.f;
#pragma unroll
      for (int r = 0; r < 8; ++r) p += f[i][r] * h[j][r];
      part[i*4+j] = p;
    }
#pragma unroll
  for (int idx = 0; idx < 16; ++idx)
#pragma unroll
    for (int o = 32; o > 0; o >>= 1) part[idx] += __shfl_xor(part[idx], o);
  if (lane == 0) {
#pragma unroll
    for (int idx = 0; idx < 16; ++idx) red[wid*16 + idx] = part[idx];
  }
  __syncthreads();
  float lg[16];
#pragma unroll
  for (int idx = 0; idx < 16; ++idx)
    lg[idx] = red[idx] + red[16+idx] + red[32+idx] + red[48+idx];

  const float scale = 0.022097086912079608f;  // 2048^-0.5
  float m[4];
#pragma unroll
  for (int j = 0; j < 4; ++j) m[j] = maskf[(size_t)cb*NT + j];
  const float denom = fmaxf(m[0]+m[1]+m[2]+m[3], 1.0f);
  float c[4] = {0.f, 0.f, 0.f, 0.f};
#pragma unroll
  for (int i = 0; i < 4; ++i) {
    float x[4];
#pragma unroll
    for (int j = 0; j < 4; ++j) x[j] = (m[j] > 0.f) ? lg[i*4+j]*scale : -1e9f;
    const float mx = fmaxf(fmaxf(x[0],x[1]), fmaxf(x[2],x[3]));
    float p[4], sum = 0.f;
#pragma unroll
    for (int j = 0; j < 4; ++j) { p[j] = expf(x[j]-mx); sum += p[j]; }
    const float w = m[i] / (sum * denom);
#pragma unroll
    for (int j = 0; j < 4; ++j) c[j] += p[j] * w;
  }
  unsigned int pk[4];
#pragma unroll
  for (int jj = 0; jj < 4; ++jj) {
    float ulo = c[0]*f[0][2*jj]   + c[1]*f[1][2*jj]   + c[2]*f[2][2*jj]   + c[3]*f[3][2*jj];
    float uhi = c[0]*f[0][2*jj+1] + c[1]*f[1][2*jj+1] + c[2]*f[2][2*jj+1] + c[3]*f[3][2*jj+1];
    pk[jj] = (unsigned int)f2bf(ulo) | ((unsigned int)f2bf(uhi) << 16);
  }
  *reinterpret_cast<uint4*>(H + (size_t)cb*4*ND + e0) = make_uint4(pk[0],pk[1],pk[2],pk[3]);
}

// ---------- deterministic loss reduce (1024 fixed slots) ----------------------
__global__ __launch_bounds__(256) void loss_final(const float* __restrict__ lpart,
                                                  float* __restrict__ out) {
  const int tid = threadIdx.x;
  float s = 0.f;
  for (int i = tid; i < 1024; i += 256) s += lpart[i];
#pragma unroll
  for (int o = 32; o > 0; o >>= 1) s += __shfl_xor(s, o);
  __shared__ float red[4];
  const int lane = tid & 63, wid = tid >> 6;
  if (lane == 0) red[wid] = s;
  __syncthreads();
  if (tid == 0) out[0] = (red[0]+red[1]+red[2]+red[3]) * (1.0f / 16777216.0f);
}

extern "C" void kernel_launch(void* const* d_in, const int* in_sizes, int n_in,
                              void* d_out, int out_size, void* d_ws, size_t ws_size,
                              hipStream_t stream) {
  const float* x_start   = (const float*)d_in[0];
  const int*   tarr      = (const int*)  d_in[1];
  const float* noise     = (const float*)d_in[2];
  const float* cond_src  = (const float*)d_in[3];
  const float* cond_tgt  = (const float*)d_in[4];
  const float* w_q       = (const float*)d_in[5];
  const float* w_k       = (const float*)d_in[6];
  const float* w_v       = (const float*)d_in[7];
  const float* sqrt_ac   = (const float*)d_in[8];
  const float* sqrt_omac = (const float*)d_in[9];
  float* out = (float*)d_out;
  char*  ws  = (char*)d_ws;

  // CB capped at 4096 (whole-batch path showed L2-locality loss, r10)
  size_t CB;
  if      (ws_size >= 151064576ull) CB = 4096;
  else if (ws_size >=  83922944ull) CB = 2048;
  else if (ws_size >=  50352128ull) CB = 1024;
  else return;

  const size_t offG  = 0;
  const size_t offWv = 8388608;
  const size_t offF  = 16777216;
  const size_t szF   = CB * 16384;            // 4*CB*2048*2 bytes
  const size_t offH  = offF + szF;
  const size_t offMask = offH + szF;
  const size_t offLp   = offMask + CB * 16;

  unsigned short* G    = (unsigned short*)(ws + offG);
  unsigned short* WvBf = (unsigned short*)(ws + offWv);
  unsigned short* F    = (unsigned short*)(ws + offF);
  unsigned short* H    = (unsigned short*)(ws + offH);
  float* maskC = (float*)(ws + offMask);
  float* lpart = (float*)(ws + offLp);
  unsigned short* WqT = F;
  unsigned short* WkT = H;

  prep_weights<<<dim3(32, 32, 3), 256, 0, stream>>>(w_q, w_k, w_v, WqT, WkT, WvBf);
  gemm_nt_bf16<<<dim3(16, 16), 256, 0, stream>>>(WqT, WkT, G);   // G = Wq^T Wk

  const int nchunks = NB / (int)CB;
  for (int ci = 0; ci < nchunks; ++ci) {
    const int b0 = ci * (int)CB;
    prep_tokens<<<dim3(NT, (int)CB), 256, 0, stream>>>(
        x_start, tarr, noise, cond_src, cond_tgt, sqrt_ac, sqrt_omac, F, maskC, b0);
    gemm_nt_256<<<dim3(ND/256, (NT*(int)CB)/256), 512, 0, stream>>>(F, G, H);  // H = F G^T
    attn_u<<<dim3((int)CB), 256, 0, stream>>>(F, H, maskC);                    // U -> H rows 4*cb
    gemm_pred_r2<<<dim3(16, (int)CB / 128), 256, 0, stream>>>(
        H /* U, lda=8192 */, WvBf, out + 1, x_start, lpart, b0);               // pred = U Wv^T
  }
  loss_final<<<dim3(1), 256, 0, stream>>>(lpart, out);
}

// Round 12
// 579.217 us; speedup vs baseline: 1.0557x; 1.0537x over previous
//
#include <hip/hip_runtime.h>
#include <math.h>

#define NB 8192
#define ND 2048
#define NT 4

using bf16x8 = __attribute__((ext_vector_type(8))) short;
using f32x4  = __attribute__((ext_vector_type(4))) float;

__device__ inline unsigned short f2bf(float f) {
  unsigned int u = __float_as_uint(f);
  u += 0x7FFFu + ((u >> 16) & 1u);           // RNE
  return (unsigned short)(u >> 16);
}
__device__ inline void unpack8(uint4 u, float* f) {
  f[0] = __uint_as_float(u.x << 16); f[1] = __uint_as_float(u.x & 0xFFFF0000u);
  f[2] = __uint_as_float(u.y << 16); f[3] = __uint_as_float(u.y & 0xFFFF0000u);
  f[4] = __uint_as_float(u.z << 16); f[5] = __uint_as_float(u.z & 0xFFFF0000u);
  f[6] = __uint_as_float(u.w << 16); f[7] = __uint_as_float(u.w & 0xFFFF0000u);
}

#define GL2LDS(g, l) __builtin_amdgcn_global_load_lds( \
    (const __attribute__((address_space(1))) void*)(g), \
    (__attribute__((address_space(3))) void*)(l), 16, 0, 0)

__device__ inline void waitv0() { asm volatile("s_waitcnt vmcnt(0)" ::: "memory"); }

// LDS bijection (per 32-k subtile, 16B chunks): slot s <-> (r=s>>2, c=(s&3)^((r>>1)&3))
// -> 8 consecutive lanes of a ds_read_b128 hit 8 distinct slot%8 groups:
// conflict-free (verified SQ_LDS_BANK_CONFLICT==0, r4-r11). Writes linear via
// global_load_lds; permutation applied to the GLOBAL source address (m173).

// ---------- merged weight prep: z=0 transpose wq, z=1 transpose wk, z=2 cast wv
__global__ __launch_bounds__(256) void prep_weights(
    const float* __restrict__ wq, const float* __restrict__ wk,
    const float* __restrict__ wv, unsigned short* __restrict__ WqT,
    unsigned short* __restrict__ WkT, unsigned short* __restrict__ WvBf)
{
  __shared__ float tile[64][65];
  const int t = threadIdx.x, r = t >> 2, c0 = (t & 3) * 16;
  const int bx = blockIdx.x * 64, by = blockIdx.y * 64;
  const int z = blockIdx.z;
  if (z == 2) {
    const float* src = wv + (size_t)(by + r) * ND + bx + c0;
    unsigned short* dst = WvBf + (size_t)(by + r) * ND + bx + c0;
    float4 v0 = *reinterpret_cast<const float4*>(src);
    float4 v1 = *reinterpret_cast<const float4*>(src + 4);
    float4 v2 = *reinterpret_cast<const float4*>(src + 8);
    float4 v3 = *reinterpret_cast<const float4*>(src + 12);
    unsigned int pk[8];
    pk[0] = f2bf(v0.x) | ((unsigned)f2bf(v0.y) << 16);
    pk[1] = f2bf(v0.z) | ((unsigned)f2bf(v0.w) << 16);
    pk[2] = f2bf(v1.x) | ((unsigned)f2bf(v1.y) << 16);
    pk[3] = f2bf(v1.z) | ((unsigned)f2bf(v1.w) << 16);
    pk[4] = f2bf(v2.x) | ((unsigned)f2bf(v2.y) << 16);
    pk[5] = f2bf(v2.z) | ((unsigned)f2bf(v2.w) << 16);
    pk[6] = f2bf(v3.x) | ((unsigned)f2bf(v3.y) << 16);
    pk[7] = f2bf(v3.z) | ((unsigned)f2bf(v3.w) << 16);
    *reinterpret_cast<uint4*>(dst)     = make_uint4(pk[0], pk[1], pk[2], pk[3]);
    *reinterpret_cast<uint4*>(dst + 8) = make_uint4(pk[4], pk[5], pk[6], pk[7]);
    return;
  }
  const float* W = (z == 0) ? wq : wk;
  unsigned short* WT = (z == 0) ? WqT : WkT;
  const float* src = W + (size_t)(by + r) * ND + bx + c0;
#pragma unroll
  for (int j = 0; j < 4; ++j) {
    float4 v = *reinterpret_cast<const float4*>(src + j * 4);
    tile[r][c0 + j*4 + 0] = v.x; tile[r][c0 + j*4 + 1] = v.y;
    tile[r][c0 + j*4 + 2] = v.z; tile[r][c0 + j*4 + 3] = v.w;
  }
  __syncthreads();
  unsigned int pk[8];
#pragma unroll
  for (int j = 0; j < 8; ++j) {
    unsigned int lo = f2bf(tile[c0 + 2*j    ][r]);
    unsigned int hi = f2bf(tile[c0 + 2*j + 1][r]);
    pk[j] = lo | (hi << 16);
  }
  unsigned short* dst = WT + (size_t)(bx + r) * ND + by + c0;
  *reinterpret_cast<uint4*>(dst)     = make_uint4(pk[0], pk[1], pk[2], pk[3]);
  *reinterpret_cast<uint4*>(dst + 8) = make_uint4(pk[4], pk[5], pk[6], pk[7]);
}

// ---------- tokens + mask + LayerNorm -> F chunk (bf16) -----------------------
__global__ __launch_bounds__(256) void prep_tokens(
    const float* __restrict__ x_start, const int* __restrict__ tarr,
    const float* __restrict__ noise, const float* __restrict__ cond_src,
    const float* __restrict__ cond_tgt, const float* __restrict__ sqrt_ac,
    const float* __restrict__ sqrt_omac, unsigned short* __restrict__ F,
    float* __restrict__ maskf, int b0)
{
  const int cb = blockIdx.y, tok = blockIdx.x, tid = threadIdx.x;
  const int b = b0 + cb;
  const int e0 = tid * 8;
  float v[8];
  if (tok == 0) {
    const int tb = tarr[b];
    const float sa = sqrt_ac[tb], so = sqrt_omac[tb];
    const float4* xs = reinterpret_cast<const float4*>(x_start + (size_t)b * ND + e0);
    const float4* ns = reinterpret_cast<const float4*>(noise + (size_t)b * ND + e0);
    float4 x0 = xs[0], x1 = xs[1], n0 = ns[0], n1 = ns[1];
    v[0] = sa*x0.x + so*n0.x; v[1] = sa*x0.y + so*n0.y;
    v[2] = sa*x0.z + so*n0.z; v[3] = sa*x0.w + so*n0.w;
    v[4] = sa*x1.x + so*n1.x; v[5] = sa*x1.y + so*n1.y;
    v[6] = sa*x1.z + so*n1.z; v[7] = sa*x1.w + so*n1.w;
  } else if (tok == 1) {
    const float tf = (float)tarr[b];
    const float cc = -9.210340371976184f / 1023.0f;  // -ln(10000)/(half-1)
#pragma unroll
    for (int j = 0; j < 8; ++j) {
      int e = e0 + j;
      int i = (e < 1024) ? e : (e - 1024);
      float a = tf * expf((float)i * cc);
      v[j] = (e < 1024) ? sinf(a) : cosf(a);
    }
  } else {
    const float* src = (tok == 2) ? cond_src : cond_tgt;
    const float4* ps = reinterpret_cast<const float4*>(src + (size_t)b * ND + e0);
    float4 a0 = ps[0], a1 = ps[1];
    v[0]=a0.x; v[1]=a0.y; v[2]=a0.z; v[3]=a0.w;
    v[4]=a1.x; v[5]=a1.y; v[6]=a1.z; v[7]=a1.w;
  }
  float s = 0.f, s2 = 0.f, sab = 0.f;
#pragma unroll
  for (int j = 0; j < 8; ++j) { s += v[j]; s2 += v[j]*v[j]; sab += fabsf(v[j]); }
#pragma unroll
  for (int o = 32; o > 0; o >>= 1) {
    s += __shfl_xor(s, o); s2 += __shfl_xor(s2, o); sab += __shfl_xor(sab, o);
  }
  __shared__ float red[12];
  const int lane = tid & 63, wid = tid >> 6;
  if (lane == 0) { red[wid*3+0] = s; red[wid*3+1] = s2; red[wid*3+2] = sab; }
  __syncthreads();
  s   = red[0] + red[3] + red[6] + red[9];
  s2  = red[1] + red[4] + red[7] + red[10];
  sab = red[2] + red[5] + red[8] + red[11];
  const float mu  = s * (1.0f / ND);
  const float var = s2 * (1.0f / ND) - mu * mu;
  const float rs  = rsqrtf(var + 1e-5f);
  if (tid == 0) maskf[(size_t)cb*NT + tok] = (sab > 0.0f) ? 1.0f : 0.0f;
  unsigned int pk[4];
#pragma unroll
  for (int j = 0; j < 4; ++j) {
    unsigned int lo = f2bf((v[2*j]   - mu) * rs);
    unsigned int hi = f2bf((v[2*j+1] - mu) * rs);
    pk[j] = lo | (hi << 16);
  }
  *reinterpret_cast<uint4*>(F + ((size_t)cb*NT + tok) * ND + e0) =
      make_uint4(pk[0], pk[1], pk[2], pk[3]);
}

// ---------- 128^2 GEMM core (swizzled LDS): C=A*B^T, bf16 out (G-GEMM) --------
__global__ __launch_bounds__(256) void gemm_nt_bf16(
    const unsigned short* __restrict__ A, const unsigned short* __restrict__ B,
    unsigned short* __restrict__ C)
{
  constexpr int K = ND;
  __shared__ unsigned short As[128*32];
  __shared__ unsigned short Bs[128*32];
  const int tid = threadIdx.x;
  const int lane = tid & 63, wid = tid >> 6;
  const int wm = wid >> 1, wn = wid & 1;
  const size_t arow0 = (size_t)blockIdx.y * 128;
  const size_t bcol0 = (size_t)blockIdx.x * 128;
  f32x4 acc[4][4] = {};
  const int row0 = tid >> 2, row1 = row0 + 64;
  const int kc = (((tid & 3) ^ ((tid >> 3) & 3))) * 8;
  const unsigned short* ga0 = A + (arow0 + row0) * K + kc;
  const unsigned short* ga1 = A + (arow0 + row1) * K + kc;
  const unsigned short* gb0 = B + (bcol0 + row0) * K + kc;
  const unsigned short* gb1 = B + (bcol0 + row1) * K + kc;
  char* lAs = (char*)As; char* lBs = (char*)Bs;
  const int lo0 = wid * 1024, lo1 = 4096 + wid * 1024;
  const int ar = (lane & 15);
  const int ko = ((lane >> 4) ^ ((lane >> 1) & 3)) * 8;
  for (int k0 = 0; k0 < K; k0 += 32) {
    GL2LDS(ga0 + k0, lAs + lo0);
    GL2LDS(ga1 + k0, lAs + lo1);
    GL2LDS(gb0 + k0, lBs + lo0);
    GL2LDS(gb1 + k0, lBs + lo1);
    __syncthreads();
    bf16x8 af[4], bfr[4];
#pragma unroll
    for (int mi = 0; mi < 4; ++mi)
      af[mi] = *reinterpret_cast<const bf16x8*>(&As[(wm*64 + mi*16 + ar)*32 + ko]);
#pragma unroll
    for (int ni = 0; ni < 4; ++ni)
      bfr[ni] = *reinterpret_cast<const bf16x8*>(&Bs[(wn*64 + ni*16 + ar)*32 + ko]);
#pragma unroll
    for (int mi = 0; mi < 4; ++mi)
#pragma unroll
      for (int ni = 0; ni < 4; ++ni)
        acc[mi][ni] = __builtin_amdgcn_mfma_f32_16x16x32_bf16(af[mi], bfr[ni], acc[mi][ni], 0, 0, 0);
    __syncthreads();
  }
#pragma unroll
  for (int mi = 0; mi < 4; ++mi)
#pragma unroll
    for (int ni = 0; ni < 4; ++ni) {
      const size_t col = bcol0 + wn*64 + ni*16 + (lane & 15);
#pragma unroll
      for (int r = 0; r < 4; ++r) {
        const size_t row = arow0 + wm*64 + mi*16 + (lane >> 4)*4 + r;
        C[row * ND + col] = f2bf(acc[mi][ni][r]);
      }
    }
}

// ---------- H-GEMM (TRUE r7 kernel): 256^2, BK=64, ring-2, quadrant interleave
// Per tile: 4 sub-phases {ds_read chunk -> 16 MFMA} pinned by sched_barrier(0);
// setprio(1) around MFMA clusters; single boundary vmcnt(0)+barrier per tile.
// Benched in Round 7: 122-130 us, MfmaUtil 46-49%.
__global__ __launch_bounds__(512, 2) void gemm_nt_256(
    const unsigned short* __restrict__ A, const unsigned short* __restrict__ B,
    unsigned short* __restrict__ C)
{
  constexpr int K = 2048;
  constexpr int NTILE = K / 64;  // 32
  __shared__ unsigned short lds[65536];  // 128 KiB: 2 rings x (A 32K + B 32K)
  const int tid = threadIdx.x;
  const int lane = tid & 63, wid = tid >> 6;
  const int wm = wid >> 2, wn = wid & 3;

  const int GX = (int)gridDim.x;
  const int nwg = GX * (int)gridDim.y;
  const int o = (int)blockIdx.y * GX + (int)blockIdx.x;
  const int swz = (o & 7) * (nwg >> 3) + (o >> 3);
  const int bx = swz % GX, by = swz / GX;

  const size_t arow0 = (size_t)by * 256;
  const size_t bcol0 = (size_t)bx * 256;
  char* ldsb = (char*)lds;

  const int s0 = wid*64 + lane, s1 = s0 + 512;
  const int rS0 = s0 >> 2, cS0 = (s0 & 3) ^ ((rS0 >> 1) & 3);
  const int rS1 = s1 >> 2, cS1 = (s1 & 3) ^ ((rS1 >> 1) & 3);
  const unsigned short* gA0 = A + (arow0 + rS0) * K + cS0*8;
  const unsigned short* gA1 = A + (arow0 + rS1) * K + cS1*8;
  const unsigned short* gB0 = B + (bcol0 + rS0) * K + cS0*8;
  const unsigned short* gB1 = B + (bcol0 + rS1) * K + cS1*8;
  const int ldsw0 = wid * 1024;
  const int ldsw1 = 8192 + wid * 1024;

#define STAGE_AH(tt,h) { const int q_ = ((tt)&1)*65536; const int k_ = (tt)*64 + (h)*32; \
    GL2LDS(gA0 + k_, ldsb + q_ + (h)*16384 + ldsw0);                                     \
    GL2LDS(gA1 + k_, ldsb + q_ + (h)*16384 + ldsw1); }
#define STAGE_BH(tt,h) { const int q_ = ((tt)&1)*65536; const int k_ = (tt)*64 + (h)*32; \
    GL2LDS(gB0 + k_, ldsb + q_ + 32768 + (h)*16384 + ldsw0);                             \
    GL2LDS(gB1 + k_, ldsb + q_ + 32768 + (h)*16384 + ldsw1); }

  const int lo16 = ((lane & 15) * 4 + ((lane >> 4) ^ ((lane >> 1) & 3))) * 16;

  f32x4 acc[8][4] = {};
  bf16x8 aq[4][2], bq[4][2];

  STAGE_AH(0,0); STAGE_AH(0,1); STAGE_BH(0,0); STAGE_BH(0,1);
  waitv0();
  __builtin_amdgcn_s_barrier();

  for (int t = 0; t < NTILE; ++t) {
    const char* rg = ldsb + (t & 1) * 65536;

    // ---- sub-phase 1 (q00): read A[0..3][*] + B[0..1][*]; stage A(t+1) ----
#pragma unroll
    for (int i = 0; i < 4; ++i)
#pragma unroll
      for (int kh = 0; kh < 2; ++kh)
        aq[i][kh] = *reinterpret_cast<const bf16x8*>(rg + kh*16384 + wm*8192 + i*1024 + lo16);
#pragma unroll
    for (int ni = 0; ni < 2; ++ni)
#pragma unroll
      for (int kh = 0; kh < 2; ++kh)
        bq[ni][kh] = *reinterpret_cast<const bf16x8*>(rg + 32768 + kh*16384 + wn*4096 + ni*1024 + lo16);
    if (t + 1 < NTILE) { STAGE_AH(t+1,0); STAGE_AH(t+1,1); }
    __builtin_amdgcn_sched_barrier(0);
    __builtin_amdgcn_s_setprio(1);
#pragma unroll
    for (int i = 0; i < 4; ++i)
#pragma unroll
      for (int ni = 0; ni < 2; ++ni)
#pragma unroll
        for (int kh = 0; kh < 2; ++kh)
          acc[i][ni] = __builtin_amdgcn_mfma_f32_16x16x32_bf16(aq[i][kh], bq[ni][kh], acc[i][ni], 0, 0, 0);
    __builtin_amdgcn_s_setprio(0);
    __builtin_amdgcn_sched_barrier(0);

    // ---- sub-phase 2 (q01): read B[2..3][*]; stage B(t+1) ----
#pragma unroll
    for (int ni = 2; ni < 4; ++ni)
#pragma unroll
      for (int kh = 0; kh < 2; ++kh)
        bq[ni][kh] = *reinterpret_cast<const bf16x8*>(rg + 32768 + kh*16384 + wn*4096 + ni*1024 + lo16);
    if (t + 1 < NTILE) { STAGE_BH(t+1,0); STAGE_BH(t+1,1); }
    __builtin_amdgcn_sched_barrier(0);
    __builtin_amdgcn_s_setprio(1);
#pragma unroll
    for (int i = 0; i < 4; ++i)
#pragma unroll
      for (int ni = 2; ni < 4; ++ni)
#pragma unroll
        for (int kh = 0; kh < 2; ++kh)
          acc[i][ni] = __builtin_amdgcn_mfma_f32_16x16x32_bf16(aq[i][kh], bq[ni][kh], acc[i][ni], 0, 0, 0);
    __builtin_amdgcn_s_setprio(0);
    __builtin_amdgcn_sched_barrier(0);

    // ---- sub-phase 3 (q11): read A[4..7][*]; MFMA vs B[2..3] ----
#pragma unroll
    for (int i = 0; i < 4; ++i)
#pragma unroll
      for (int kh = 0; kh < 2; ++kh)
        aq[i][kh] = *reinterpret_cast<const bf16x8*>(rg + kh*16384 + wm*8192 + (i+4)*1024 + lo16);
    __builtin_amdgcn_sched_barrier(0);
    __builtin_amdgcn_s_setprio(1);
#pragma unroll
    for (int i = 0; i < 4; ++i)
#pragma unroll
      for (int ni = 2; ni < 4; ++ni)
#pragma unroll
        for (int kh = 0; kh < 2; ++kh)
          acc[i+4][ni] = __builtin_amdgcn_mfma_f32_16x16x32_bf16(aq[i][kh], bq[ni][kh], acc[i+4][ni], 0, 0, 0);
    __builtin_amdgcn_s_setprio(0);
    __builtin_amdgcn_sched_barrier(0);

    // ---- sub-phase 4 (q10): no reads; MFMA vs B[0..1] ----
    __builtin_amdgcn_s_setprio(1);
#pragma unroll
    for (int i = 0; i < 4; ++i)
#pragma unroll
      for (int ni = 0; ni < 2; ++ni)
#pragma unroll
        for (int kh = 0; kh < 2; ++kh)
          acc[i+4][ni] = __builtin_amdgcn_mfma_f32_16x16x32_bf16(aq[i][kh], bq[ni][kh], acc[i+4][ni], 0, 0, 0);
    __builtin_amdgcn_s_setprio(0);

    // ---- boundary: t+1's 8 loads (issued >=2 sub-phases ago) -> sync ----
    waitv0();
    __builtin_amdgcn_s_barrier();
  }
#undef STAGE_AH
#undef STAGE_BH

#pragma unroll
  for (int mi = 0; mi < 8; ++mi)
#pragma unroll
    for (int ni = 0; ni < 4; ++ni) {
      const size_t col = bcol0 + wn*64 + ni*16 + (lane & 15);
#pragma unroll
      for (int r = 0; r < 4; ++r) {
        const size_t row = arow0 + wm*128 + mi*16 + (lane >> 4)*4 + r;
        C[row * 2048 + col] = f2bf(acc[mi][ni][r]);
      }
    }
}

// ---------- pred GEMM: 128^2, BK=32, RING-2 (32 KiB), 4 blocks/CU -------------
#define LDA_U 8192
__global__ __launch_bounds__(256, 4) void gemm_pred_r2(
    const unsigned short* __restrict__ A, const unsigned short* __restrict__ B,
    float* __restrict__ outp /* = out+1 */, const float* __restrict__ x_start,
    float* __restrict__ lpart, int b0)
{
  constexpr int K = ND;
  constexpr int NTILE = K / 32;   // 64
  __shared__ unsigned short lds[16384];  // 32 KiB: 2 rings x (A 8K + B 8K)
  __shared__ float r2[4];
  const int tid = threadIdx.x;
  const int lane = tid & 63, wid = tid >> 6;
  const int wm = wid >> 1, wn = wid & 1;

  const int GX = (int)gridDim.x;   // 16
  const int nwg = GX * (int)gridDim.y;
  const int o = (int)blockIdx.y * GX + (int)blockIdx.x;
  const int swz = (o & 7) * (nwg >> 3) + (o >> 3);
  const int bx = swz % GX, by = swz / GX;
  const size_t arow0 = (size_t)by * 128;
  const size_t bcol0 = (size_t)bx * 128;
  char* ldsb = (char*)lds;

  const int row0 = tid >> 2, row1 = row0 + 64;
  const int kc = (((tid & 3) ^ ((tid >> 3) & 3))) * 8;
  const unsigned short* ga0 = A + (arow0 + row0) * LDA_U + kc;
  const unsigned short* ga1 = A + (arow0 + row1) * LDA_U + kc;
  const unsigned short* gb0 = B + (bcol0 + row0) * K + kc;
  const unsigned short* gb1 = B + (bcol0 + row1) * K + kc;
  const int lo0 = wid * 1024, lo1 = 4096 + wid * 1024;

#define STAGE(tt) { const int q_ = ((tt)&1)*16384; const int k_ = (tt)*32; \
    GL2LDS(ga0 + k_, ldsb + q_ + lo0);                                     \
    GL2LDS(ga1 + k_, ldsb + q_ + lo1);                                     \
    GL2LDS(gb0 + k_, ldsb + q_ + 8192 + lo0);                              \
    GL2LDS(gb1 + k_, ldsb + q_ + 8192 + lo1); }

  const int ar = (lane & 15);
  const int ko2 = ((lane >> 4) ^ ((lane >> 1) & 3)) * 16;  // bytes

  f32x4 acc[4][4] = {};

  STAGE(0);
  waitv0();
  __builtin_amdgcn_s_barrier();

  for (int t = 0; t < NTILE; ++t) {
    const char* rg = ldsb + (t & 1) * 16384;
    bf16x8 af[4], bfr[4];
#pragma unroll
    for (int mi = 0; mi < 4; ++mi)
      af[mi] = *reinterpret_cast<const bf16x8*>(rg + (wm*64 + mi*16 + ar)*64 + ko2);
#pragma unroll
    for (int ni = 0; ni < 4; ++ni)
      bfr[ni] = *reinterpret_cast<const bf16x8*>(rg + 8192 + (wn*64 + ni*16 + ar)*64 + ko2);
    if (t + 1 < NTILE) STAGE(t + 1);
    __builtin_amdgcn_s_setprio(1);
#pragma unroll
    for (int mi = 0; mi < 4; ++mi)
#pragma unroll
      for (int ni = 0; ni < 4; ++ni)
        acc[mi][ni] = __builtin_amdgcn_mfma_f32_16x16x32_bf16(af[mi], bfr[ni], acc[mi][ni], 0, 0, 0);
    __builtin_amdgcn_s_setprio(0);
    if (t + 1 < NTILE) waitv0();
    __builtin_amdgcn_s_barrier();
  }
#undef STAGE

  float sse = 0.f;
#pragma unroll
  for (int mi = 0; mi < 4; ++mi)
#pragma unroll
    for (int ni = 0; ni < 4; ++ni) {
      const size_t col = bcol0 + wn*64 + ni*16 + (lane & 15);
#pragma unroll
      for (int r = 0; r < 4; ++r) {
        const size_t row = arow0 + wm*64 + mi*16 + (lane >> 4)*4 + r;  // chunk-local b
        const size_t gb  = (size_t)b0 + row;                           // global b
        const float p = acc[mi][ni][r];
        outp[gb * ND + col] = p;
        const float d = p - x_start[gb * ND + col];
        sse += d * d;
      }
    }
#pragma unroll
  for (int o2 = 32; o2 > 0; o2 >>= 1) sse += __shfl_xor(sse, o2);
  if (lane == 0) r2[wid] = sse;
  __syncthreads();
  if (tid == 0) {
    const int slot = ((b0 >> 7) + by) * 16 + bx;
    lpart[slot] = r2[0] + r2[1] + r2[2] + r2[3];
  }
}

// ---------- per-group: logits -> softmax -> U row written OVER H row 4*cb -----
__global__ __launch_bounds__(256) void attn_u(
    const unsigned short* __restrict__ F, unsigned short* __restrict__ H,
    const float* __restrict__ maskf)
{
  const int cb = blockIdx.x, tid = threadIdx.x;
  const int e0 = tid * 8, lane = tid & 63, wid = tid >> 6;
  __shared__ float red[64];
  float f[4][8], h[4][8];
#pragma unroll
  for (int i = 0; i < 4; ++i) {
    unpack8(*reinterpret_cast<const uint4*>(F + ((size_t)cb*4 + i)*ND + e0), f[i]);
    unpack8(*reinterpret_cast<const uint4*>(H + ((size_t)cb*4 + i)*ND + e0), h[i]);
  }
  float part[16];
#pragma unroll
  for (int i = 0; i < 4; ++i)
#pragma unroll
    for (int j = 0; j < 4; ++j) {
      float p = 0.f;
#pragma unroll
      for (int r = 0; r < 8; ++r) p += f[i][r] * h[j][r];
      part[i*4+j] = p;
    }
#pragma unroll
  for (int idx = 0; idx < 16; ++idx)
#pragma unroll
    for (int o = 32; o > 0; o >>= 1) part[idx] += __shfl_xor(part[idx], o);
  if (lane == 0) {
#pragma unroll
    for (int idx = 0; idx < 16; ++idx) red[wid*16 + idx] = part[idx];
  }
  __syncthreads();
  float lg[16];
#pragma unroll
  for (int idx = 0; idx < 16; ++idx)
    lg[idx] = red[idx] + red[16+idx] + red[32+idx] + red[48+idx];

  const float scale = 0.022097086912079608f;  // 2048^-0.5
  float m[4];
#pragma unroll
  for (int j = 0; j < 4; ++j) m[j] = maskf[(size_t)cb*NT + j];
  const float denom = fmaxf(m[0]+m[1]+m[2]+m[3], 1.0f);
  float c[4] = {0.f, 0.f, 0.f, 0.f};
#pragma unroll
  for (int i = 0; i < 4; ++i) {
    float x[4];
#pragma unroll
    for (int j = 0; j < 4; ++j) x[j] = (m[j] > 0.f) ? lg[i*4+j]*scale : -1e9f;
    const float mx = fmaxf(fmaxf(x[0],x[1]), fmaxf(x[2],x[3]));
    float p[4], sum = 0.f;
#pragma unroll
    for (int j = 0; j < 4; ++j) { p[j] = expf(x[j]-mx); sum += p[j]; }
    const float w = m[i] / (sum * denom);
#pragma unroll
    for (int j = 0; j < 4; ++j) c[j] += p[j] * w;
  }
  unsigned int pk[4];
#pragma unroll
  for (int jj = 0; jj < 4; ++jj) {
    float ulo = c[0]*f[0][2*jj]   + c[1]*f[1][2*jj]   + c[2]*f[2][2*jj]   + c[3]*f[3][2*jj];
    float uhi = c[0]*f[0][2*jj+1] + c[1]*f[1][2*jj+1] + c[2]*f[2][2*jj+1] + c[3]*f[3][2*jj+1];
    pk[jj] = (unsigned int)f2bf(ulo) | ((unsigned int)f2bf(uhi) << 16);
  }
  *reinterpret_cast<uint4*>(H + (size_t)cb*4*ND + e0) = make_uint4(pk[0],pk[1],pk[2],pk[3]);
}

// ---------- deterministic loss reduce (1024 fixed slots) ----------------------
__global__ __launch_bounds__(256) void loss_final(const float* __restrict__ lpart,
                                                  float* __restrict__ out) {
  const int tid = threadIdx.x;
  float s = 0.f;
  for (int i = tid; i < 1024; i += 256) s += lpart[i];
#pragma unroll
  for (int o = 32; o > 0; o >>= 1) s += __shfl_xor(s, o);
  __shared__ float red[4];
  const int lane = tid & 63, wid = tid >> 6;
  if (lane == 0) red[wid] = s;
  __syncthreads();
  if (tid == 0) out[0] = (red[0]+red[1]+red[2]+red[3]) * (1.0f / 16777216.0f);
}

extern "C" void kernel_launch(void* const* d_in, const int* in_sizes, int n_in,
                              void* d_out, int out_size, void* d_ws, size_t ws_size,
                              hipStream_t stream) {
  const float* x_start   = (const float*)d_in[0];
  const int*   tarr      = (const int*)  d_in[1];
  const float* noise     = (const float*)d_in[2];
  const float* cond_src  = (const float*)d_in[3];
  const float* cond_tgt  = (const float*)d_in[4];
  const float* w_q       = (const float*)d_in[5];
  const float* w_k       = (const float*)d_in[6];
  const float* w_v       = (const float*)d_in[7];
  const float* sqrt_ac   = (const float*)d_in[8];
  const float* sqrt_omac = (const float*)d_in[9];
  float* out = (float*)d_out;
  char*  ws  = (char*)d_ws;

  // CB capped at 4096 (whole-batch path showed L2-locality loss, r10)
  size_t CB;
  if      (ws_size >= 151064576ull) CB = 4096;
  else if (ws_size >=  83922944ull) CB = 2048;
  else if (ws_size >=  50352128ull) CB = 1024;
  else return;

  const size_t offG  = 0;
  const size_t offWv = 8388608;
  const size_t offF  = 16777216;
  const size_t szF   = CB * 16384;            // 4*CB*2048*2 bytes
  const size_t offH  = offF + szF;
  const size_t offMask = offH + szF;
  const size_t offLp   = offMask + CB * 16;

  unsigned short* G    = (unsigned short*)(ws + offG);
  unsigned short* WvBf = (unsigned short*)(ws + offWv);
  unsigned short* F    = (unsigned short*)(ws + offF);
  unsigned short* H    = (unsigned short*)(ws + offH);
  float* maskC = (float*)(ws + offMask);
  float* lpart = (float*)(ws + offLp);
  unsigned short* WqT = F;
  unsigned short* WkT = H;

  prep_weights<<<dim3(32, 32, 3), 256, 0, stream>>>(w_q, w_k, w_v, WqT, WkT, WvBf);
  gemm_nt_bf16<<<dim3(16, 16), 256, 0, stream>>>(WqT, WkT, G);   // G = Wq^T Wk

  const int nchunks = NB / (int)CB;
  for (int ci = 0; ci < nchunks; ++ci) {
    const int b0 = ci * (int)CB;
    prep_tokens<<<dim3(NT, (int)CB), 256, 0, stream>>>(
        x_start, tarr, noise, cond_src, cond_tgt, sqrt_ac, sqrt_omac, F, maskC, b0);
    gemm_nt_256<<<dim3(ND/256, (NT*(int)CB)/256), 512, 0, stream>>>(F, G, H);  // H = F G^T
    attn_u<<<dim3((int)CB), 256, 0, stream>>>(F, H, maskC);                    // U -> H rows 4*cb
    gemm_pred_r2<<<dim3(16, (int)CB / 128), 256, 0, stream>>>(
        H /* U, lda=8192 */, WvBf, out + 1, x_start, lpart, b0);               // pred = U Wv^T
  }
  loss_final<<<dim3(1), 256, 0, stream>>>(lpart, out);
}

// Round 13
// 575.606 us; speedup vs baseline: 1.0624x; 1.0063x over previous
//
#include <hip/hip_runtime.h>
#include <math.h>

#define NB 8192
#define ND 2048
#define NT 4

using bf16x8 = __attribute__((ext_vector_type(8))) short;
using f32x4  = __attribute__((ext_vector_type(4))) float;

__device__ inline unsigned short f2bf(float f) {
  unsigned int u = __float_as_uint(f);
  u += 0x7FFFu + ((u >> 16) & 1u);           // RNE
  return (unsigned short)(u >> 16);
}
__device__ inline float bf2f(unsigned short s) {
  return __uint_as_float(((unsigned int)s) << 16);
}
__device__ inline void unpack8(uint4 u, float* f) {
  f[0] = __uint_as_float(u.x << 16); f[1] = __uint_as_float(u.x & 0xFFFF0000u);
  f[2] = __uint_as_float(u.y << 16); f[3] = __uint_as_float(u.y & 0xFFFF0000u);
  f[4] = __uint_as_float(u.z << 16); f[5] = __uint_as_float(u.z & 0xFFFF0000u);
  f[6] = __uint_as_float(u.w << 16); f[7] = __uint_as_float(u.w & 0xFFFF0000u);
}

#define GL2LDS(g, l) __builtin_amdgcn_global_load_lds( \
    (const __attribute__((address_space(1))) void*)(g), \
    (__attribute__((address_space(3))) void*)(l), 16, 0, 0)

__device__ inline void waitv0() { asm volatile("s_waitcnt vmcnt(0)" ::: "memory"); }

// LDS bijection (per 32-k subtile, 16B chunks): slot s <-> (r=s>>2, c=(s&3)^((r>>1)&3))
// -> conflict-free ds_read_b128 (verified SQ_LDS_BANK_CONFLICT==0, r4-r12).

// ---------- merged weight prep: z=0 transpose wq, z=1 transpose wk, z=2 cast wv
__global__ __launch_bounds__(256) void prep_weights(
    const float* __restrict__ wq, const float* __restrict__ wk,
    const float* __restrict__ wv, unsigned short* __restrict__ WqT,
    unsigned short* __restrict__ WkT, unsigned short* __restrict__ WvBf)
{
  __shared__ float tile[64][65];
  const int t = threadIdx.x, r = t >> 2, c0 = (t & 3) * 16;
  const int bx = blockIdx.x * 64, by = blockIdx.y * 64;
  const int z = blockIdx.z;
  if (z == 2) {
    const float* src = wv + (size_t)(by + r) * ND + bx + c0;
    unsigned short* dst = WvBf + (size_t)(by + r) * ND + bx + c0;
    float4 v0 = *reinterpret_cast<const float4*>(src);
    float4 v1 = *reinterpret_cast<const float4*>(src + 4);
    float4 v2 = *reinterpret_cast<const float4*>(src + 8);
    float4 v3 = *reinterpret_cast<const float4*>(src + 12);
    unsigned int pk[8];
    pk[0] = f2bf(v0.x) | ((unsigned)f2bf(v0.y) << 16);
    pk[1] = f2bf(v0.z) | ((unsigned)f2bf(v0.w) << 16);
    pk[2] = f2bf(v1.x) | ((unsigned)f2bf(v1.y) << 16);
    pk[3] = f2bf(v1.z) | ((unsigned)f2bf(v1.w) << 16);
    pk[4] = f2bf(v2.x) | ((unsigned)f2bf(v2.y) << 16);
    pk[5] = f2bf(v2.z) | ((unsigned)f2bf(v2.w) << 16);
    pk[6] = f2bf(v3.x) | ((unsigned)f2bf(v3.y) << 16);
    pk[7] = f2bf(v3.z) | ((unsigned)f2bf(v3.w) << 16);
    *reinterpret_cast<uint4*>(dst)     = make_uint4(pk[0], pk[1], pk[2], pk[3]);
    *reinterpret_cast<uint4*>(dst + 8) = make_uint4(pk[4], pk[5], pk[6], pk[7]);
    return;
  }
  const float* W = (z == 0) ? wq : wk;
  unsigned short* WT = (z == 0) ? WqT : WkT;
  const float* src = W + (size_t)(by + r) * ND + bx + c0;
#pragma unroll
  for (int j = 0; j < 4; ++j) {
    float4 v = *reinterpret_cast<const float4*>(src + j * 4);
    tile[r][c0 + j*4 + 0] = v.x; tile[r][c0 + j*4 + 1] = v.y;
    tile[r][c0 + j*4 + 2] = v.z; tile[r][c0 + j*4 + 3] = v.w;
  }
  __syncthreads();
  unsigned int pk[8];
#pragma unroll
  for (int j = 0; j < 8; ++j) {
    unsigned int lo = f2bf(tile[c0 + 2*j    ][r]);
    unsigned int hi = f2bf(tile[c0 + 2*j + 1][r]);
    pk[j] = lo | (hi << 16);
  }
  unsigned short* dst = WT + (size_t)(bx + r) * ND + by + c0;
  *reinterpret_cast<uint4*>(dst)     = make_uint4(pk[0], pk[1], pk[2], pk[3]);
  *reinterpret_cast<uint4*>(dst + 8) = make_uint4(pk[4], pk[5], pk[6], pk[7]);
}

// ---------- tokens + mask + LayerNorm -> F chunk (bf16) -----------------------
__global__ __launch_bounds__(256) void prep_tokens(
    const float* __restrict__ x_start, const int* __restrict__ tarr,
    const float* __restrict__ noise, const float* __restrict__ cond_src,
    const float* __restrict__ cond_tgt, const float* __restrict__ sqrt_ac,
    const float* __restrict__ sqrt_omac, unsigned short* __restrict__ F,
    float* __restrict__ maskf, int b0)
{
  const int cb = blockIdx.y, tok = blockIdx.x, tid = threadIdx.x;
  const int b = b0 + cb;
  const int e0 = tid * 8;
  float v[8];
  if (tok == 0) {
    const int tb = tarr[b];
    const float sa = sqrt_ac[tb], so = sqrt_omac[tb];
    const float4* xs = reinterpret_cast<const float4*>(x_start + (size_t)b * ND + e0);
    const float4* ns = reinterpret_cast<const float4*>(noise + (size_t)b * ND + e0);
    float4 x0 = xs[0], x1 = xs[1], n0 = ns[0], n1 = ns[1];
    v[0] = sa*x0.x + so*n0.x; v[1] = sa*x0.y + so*n0.y;
    v[2] = sa*x0.z + so*n0.z; v[3] = sa*x0.w + so*n0.w;
    v[4] = sa*x1.x + so*n1.x; v[5] = sa*x1.y + so*n1.y;
    v[6] = sa*x1.z + so*n1.z; v[7] = sa*x1.w + so*n1.w;
  } else if (tok == 1) {
    const float tf = (float)tarr[b];
    const float cc = -9.210340371976184f / 1023.0f;  // -ln(10000)/(half-1)
#pragma unroll
    for (int j = 0; j < 8; ++j) {
      int e = e0 + j;
      int i = (e < 1024) ? e : (e - 1024);
      float a = tf * expf((float)i * cc);
      v[j] = (e < 1024) ? sinf(a) : cosf(a);
    }
  } else {
    const float* src = (tok == 2) ? cond_src : cond_tgt;
    const float4* ps = reinterpret_cast<const float4*>(src + (size_t)b * ND + e0);
    float4 a0 = ps[0], a1 = ps[1];
    v[0]=a0.x; v[1]=a0.y; v[2]=a0.z; v[3]=a0.w;
    v[4]=a1.x; v[5]=a1.y; v[6]=a1.z; v[7]=a1.w;
  }
  float s = 0.f, s2 = 0.f, sab = 0.f;
#pragma unroll
  for (int j = 0; j < 8; ++j) { s += v[j]; s2 += v[j]*v[j]; sab += fabsf(v[j]); }
#pragma unroll
  for (int o = 32; o > 0; o >>= 1) {
    s += __shfl_xor(s, o); s2 += __shfl_xor(s2, o); sab += __shfl_xor(sab, o);
  }
  __shared__ float red[12];
  const int lane = tid & 63, wid = tid >> 6;
  if (lane == 0) { red[wid*3+0] = s; red[wid*3+1] = s2; red[wid*3+2] = sab; }
  __syncthreads();
  s   = red[0] + red[3] + red[6] + red[9];
  s2  = red[1] + red[4] + red[7] + red[10];
  sab = red[2] + red[5] + red[8] + red[11];
  const float mu  = s * (1.0f / ND);
  const float var = s2 * (1.0f / ND) - mu * mu;
  const float rs  = rsqrtf(var + 1e-5f);
  if (tid == 0) maskf[(size_t)cb*NT + tok] = (sab > 0.0f) ? 1.0f : 0.0f;
  unsigned int pk[4];
#pragma unroll
  for (int j = 0; j < 4; ++j) {
    unsigned int lo = f2bf((v[2*j]   - mu) * rs);
    unsigned int hi = f2bf((v[2*j+1] - mu) * rs);
    pk[j] = lo | (hi << 16);
  }
  *reinterpret_cast<uint4*>(F + ((size_t)cb*NT + tok) * ND + e0) =
      make_uint4(pk[0], pk[1], pk[2], pk[3]);
}

// ---------- 128^2 GEMM core (swizzled LDS): C=A*B^T, bf16 out (G-GEMM) --------
__global__ __launch_bounds__(256) void gemm_nt_bf16(
    const unsigned short* __restrict__ A, const unsigned short* __restrict__ B,
    unsigned short* __restrict__ C)
{
  constexpr int K = ND;
  __shared__ unsigned short As[128*32];
  __shared__ unsigned short Bs[128*32];
  const int tid = threadIdx.x;
  const int lane = tid & 63, wid = tid >> 6;
  const int wm = wid >> 1, wn = wid & 1;
  const size_t arow0 = (size_t)blockIdx.y * 128;
  const size_t bcol0 = (size_t)blockIdx.x * 128;
  f32x4 acc[4][4] = {};
  const int row0 = tid >> 2, row1 = row0 + 64;
  const int kc = (((tid & 3) ^ ((tid >> 3) & 3))) * 8;
  const unsigned short* ga0 = A + (arow0 + row0) * K + kc;
  const unsigned short* ga1 = A + (arow0 + row1) * K + kc;
  const unsigned short* gb0 = B + (bcol0 + row0) * K + kc;
  const unsigned short* gb1 = B + (bcol0 + row1) * K + kc;
  char* lAs = (char*)As; char* lBs = (char*)Bs;
  const int lo0 = wid * 1024, lo1 = 4096 + wid * 1024;
  const int ar = (lane & 15);
  const int ko = ((lane >> 4) ^ ((lane >> 1) & 3)) * 8;
  for (int k0 = 0; k0 < K; k0 += 32) {
    GL2LDS(ga0 + k0, lAs + lo0);
    GL2LDS(ga1 + k0, lAs + lo1);
    GL2LDS(gb0 + k0, lBs + lo0);
    GL2LDS(gb1 + k0, lBs + lo1);
    __syncthreads();
    bf16x8 af[4], bfr[4];
#pragma unroll
    for (int mi = 0; mi < 4; ++mi)
      af[mi] = *reinterpret_cast<const bf16x8*>(&As[(wm*64 + mi*16 + ar)*32 + ko]);
#pragma unroll
    for (int ni = 0; ni < 4; ++ni)
      bfr[ni] = *reinterpret_cast<const bf16x8*>(&Bs[(wn*64 + ni*16 + ar)*32 + ko]);
#pragma unroll
    for (int mi = 0; mi < 4; ++mi)
#pragma unroll
      for (int ni = 0; ni < 4; ++ni)
        acc[mi][ni] = __builtin_amdgcn_mfma_f32_16x16x32_bf16(af[mi], bfr[ni], acc[mi][ni], 0, 0, 0);
    __syncthreads();
  }
#pragma unroll
  for (int mi = 0; mi < 4; ++mi)
#pragma unroll
    for (int ni = 0; ni < 4; ++ni) {
      const size_t col = bcol0 + wn*64 + ni*16 + (lane & 15);
#pragma unroll
      for (int r = 0; r < 4; ++r) {
        const size_t row = arow0 + wm*64 + mi*16 + (lane >> 4)*4 + r;
        C[row * ND + col] = f2bf(acc[mi][ni][r]);
      }
    }
}

// ---------- H-GEMM (r7 core) + FUSED partial-logit epilogue -------------------
// K-loop identical to r12 (122-127us, MfmaUtil 48%). Epilogue: instead of
// writing H (64MB), compute partial logits pl[i*4+j] = sum_c F[g4+i][c]*acc_j[c]
// over this (bx,wn) 64-col slice. Lane's 4 acc r-values = one group's 4 rows
// (row = ...+(lane>>4)*4+r), so products are lane-local; reduce over the 16
// col-lanes via shfl_xor(1,2,4,8); one 64B record per (group, p=bx*4+wn).
// Each of the 32 p-slots written exactly once -> no atomics, no zeroing.
__global__ __launch_bounds__(512, 2) void gemm_nt_256(
    const unsigned short* __restrict__ A, const unsigned short* __restrict__ B,
    float* __restrict__ plog, int ngroups)
{
  constexpr int K = 2048;
  constexpr int NTILE = K / 64;  // 32
  __shared__ unsigned short lds[65536];  // 128 KiB: 2 rings x (A 32K + B 32K)
  const int tid = threadIdx.x;
  const int lane = tid & 63, wid = tid >> 6;
  const int wm = wid >> 2, wn = wid & 3;

  const int GX = (int)gridDim.x;
  const int nwg = GX * (int)gridDim.y;
  const int o = (int)blockIdx.y * GX + (int)blockIdx.x;
  const int swz = (o & 7) * (nwg >> 3) + (o >> 3);
  const int bx = swz % GX, by = swz / GX;

  const size_t arow0 = (size_t)by * 256;
  const size_t bcol0 = (size_t)bx * 256;
  char* ldsb = (char*)lds;

  const int s0 = wid*64 + lane, s1 = s0 + 512;
  const int rS0 = s0 >> 2, cS0 = (s0 & 3) ^ ((rS0 >> 1) & 3);
  const int rS1 = s1 >> 2, cS1 = (s1 & 3) ^ ((rS1 >> 1) & 3);
  const unsigned short* gA0 = A + (arow0 + rS0) * K + cS0*8;
  const unsigned short* gA1 = A + (arow0 + rS1) * K + cS1*8;
  const unsigned short* gB0 = B + (bcol0 + rS0) * K + cS0*8;
  const unsigned short* gB1 = B + (bcol0 + rS1) * K + cS1*8;
  const int ldsw0 = wid * 1024;
  const int ldsw1 = 8192 + wid * 1024;

#define STAGE_AH(tt,h) { const int q_ = ((tt)&1)*65536; const int k_ = (tt)*64 + (h)*32; \
    GL2LDS(gA0 + k_, ldsb + q_ + (h)*16384 + ldsw0);                                     \
    GL2LDS(gA1 + k_, ldsb + q_ + (h)*16384 + ldsw1); }
#define STAGE_BH(tt,h) { const int q_ = ((tt)&1)*65536; const int k_ = (tt)*64 + (h)*32; \
    GL2LDS(gB0 + k_, ldsb + q_ + 32768 + (h)*16384 + ldsw0);                             \
    GL2LDS(gB1 + k_, ldsb + q_ + 32768 + (h)*16384 + ldsw1); }

  const int lo16 = ((lane & 15) * 4 + ((lane >> 4) ^ ((lane >> 1) & 3))) * 16;

  f32x4 acc[8][4] = {};
  bf16x8 aq[4][2], bq[4][2];

  STAGE_AH(0,0); STAGE_AH(0,1); STAGE_BH(0,0); STAGE_BH(0,1);
  waitv0();
  __builtin_amdgcn_s_barrier();

  for (int t = 0; t < NTILE; ++t) {
    const char* rg = ldsb + (t & 1) * 65536;

    // ---- sub-phase 1 (q00): read A[0..3][*] + B[0..1][*]; stage A(t+1) ----
#pragma unroll
    for (int i = 0; i < 4; ++i)
#pragma unroll
      for (int kh = 0; kh < 2; ++kh)
        aq[i][kh] = *reinterpret_cast<const bf16x8*>(rg + kh*16384 + wm*8192 + i*1024 + lo16);
#pragma unroll
    for (int ni = 0; ni < 2; ++ni)
#pragma unroll
      for (int kh = 0; kh < 2; ++kh)
        bq[ni][kh] = *reinterpret_cast<const bf16x8*>(rg + 32768 + kh*16384 + wn*4096 + ni*1024 + lo16);
    if (t + 1 < NTILE) { STAGE_AH(t+1,0); STAGE_AH(t+1,1); }
    __builtin_amdgcn_sched_barrier(0);
    __builtin_amdgcn_s_setprio(1);
#pragma unroll
    for (int i = 0; i < 4; ++i)
#pragma unroll
      for (int ni = 0; ni < 2; ++ni)
#pragma unroll
        for (int kh = 0; kh < 2; ++kh)
          acc[i][ni] = __builtin_amdgcn_mfma_f32_16x16x32_bf16(aq[i][kh], bq[ni][kh], acc[i][ni], 0, 0, 0);
    __builtin_amdgcn_s_setprio(0);
    __builtin_amdgcn_sched_barrier(0);

    // ---- sub-phase 2 (q01): read B[2..3][*]; stage B(t+1) ----
#pragma unroll
    for (int ni = 2; ni < 4; ++ni)
#pragma unroll
      for (int kh = 0; kh < 2; ++kh)
        bq[ni][kh] = *reinterpret_cast<const bf16x8*>(rg + 32768 + kh*16384 + wn*4096 + ni*1024 + lo16);
    if (t + 1 < NTILE) { STAGE_BH(t+1,0); STAGE_BH(t+1,1); }
    __builtin_amdgcn_sched_barrier(0);
    __builtin_amdgcn_s_setprio(1);
#pragma unroll
    for (int i = 0; i < 4; ++i)
#pragma unroll
      for (int ni = 2; ni < 4; ++ni)
#pragma unroll
        for (int kh = 0; kh < 2; ++kh)
          acc[i][ni] = __builtin_amdgcn_mfma_f32_16x16x32_bf16(aq[i][kh], bq[ni][kh], acc[i][ni], 0, 0, 0);
    __builtin_amdgcn_s_setprio(0);
    __builtin_amdgcn_sched_barrier(0);

    // ---- sub-phase 3 (q11): read A[4..7][*]; MFMA vs B[2..3] ----
#pragma unroll
    for (int i = 0; i < 4; ++i)
#pragma unroll
      for (int kh = 0; kh < 2; ++kh)
        aq[i][kh] = *reinterpret_cast<const bf16x8*>(rg + kh*16384 + wm*8192 + (i+4)*1024 + lo16);
    __builtin_amdgcn_sched_barrier(0);
    __builtin_amdgcn_s_setprio(1);
#pragma unroll
    for (int i = 0; i < 4; ++i)
#pragma unroll
      for (int ni = 2; ni < 4; ++ni)
#pragma unroll
        for (int kh = 0; kh < 2; ++kh)
          acc[i+4][ni] = __builtin_amdgcn_mfma_f32_16x16x32_bf16(aq[i][kh], bq[ni][kh], acc[i+4][ni], 0, 0, 0);
    __builtin_amdgcn_s_setprio(0);
    __builtin_amdgcn_sched_barrier(0);

    // ---- sub-phase 4 (q10): no reads; MFMA vs B[0..1] ----
    __builtin_amdgcn_s_setprio(1);
#pragma unroll
    for (int i = 0; i < 4; ++i)
#pragma unroll
      for (int ni = 0; ni < 2; ++ni)
#pragma unroll
        for (int kh = 0; kh < 2; ++kh)
          acc[i+4][ni] = __builtin_amdgcn_mfma_f32_16x16x32_bf16(aq[i][kh], bq[ni][kh], acc[i+4][ni], 0, 0, 0);
    __builtin_amdgcn_s_setprio(0);

    // ---- boundary: t+1's 8 loads (issued >=2 sub-phases ago) -> sync ----
    waitv0();
    __builtin_amdgcn_s_barrier();
  }
#undef STAGE_AH
#undef STAGE_BH

  // ---- fused epilogue: partial logits for this (bx, wn) 64-col slice ----
  const int li = lane & 15, lc = lane >> 4;
  const int p = bx * 4 + wn;                       // col-slice id, 0..31
#pragma unroll
  for (int mi = 0; mi < 8; ++mi) {
    float pl[16];
#pragma unroll
    for (int q = 0; q < 16; ++q) pl[q] = 0.f;
    const size_t r0 = arow0 + wm*128 + mi*16 + lc*4;   // group's 4 token rows
#pragma unroll
    for (int ni = 0; ni < 4; ++ni) {
      const size_t col = bcol0 + wn*64 + ni*16 + li;
      float fv[4];
#pragma unroll
      for (int i = 0; i < 4; ++i)
        fv[i] = bf2f(A[(r0 + i) * K + col]);           // A == F (L2-hot)
#pragma unroll
      for (int i = 0; i < 4; ++i)
#pragma unroll
        for (int j = 0; j < 4; ++j)
          pl[i*4+j] += fv[i] * acc[mi][ni][j];
    }
#pragma unroll
    for (int q = 0; q < 16; ++q) {
      pl[q] += __shfl_xor(pl[q], 1);
      pl[q] += __shfl_xor(pl[q], 2);
      pl[q] += __shfl_xor(pl[q], 4);
      pl[q] += __shfl_xor(pl[q], 8);
    }
    // lane li writes element li (compile-time-indexed select, no scratch)
    float vsel = 0.f;
#pragma unroll
    for (int q = 0; q < 16; ++q) vsel = (li == q) ? pl[q] : vsel;
    const int g = (int)(arow0 >> 2) + wm*32 + mi*4 + lc;   // chunk-local group
    plog[((size_t)g * 32 + p) * 16 + li] = vsel;
  }
}

// ---------- per-group: sum partials -> softmax -> U = sum_j c_j f_j -----------
__global__ __launch_bounds__(256) void u_from_logits(
    const unsigned short* __restrict__ F, const float* __restrict__ plog,
    const float* __restrict__ maskf, unsigned short* __restrict__ U)
{
  const int g = blockIdx.x, tid = threadIdx.x;
  __shared__ float lgs[16];
  if (tid < 16) {
    float s = 0.f;
    const float* base = plog + (size_t)g * 512 + tid;
    for (int p = 0; p < 32; ++p) s += base[p * 16];
    lgs[tid] = s;
  }
  __syncthreads();
  float lg[16];
#pragma unroll
  for (int q = 0; q < 16; ++q) lg[q] = lgs[q];

  const float scale = 0.022097086912079608f;  // 2048^-0.5
  float m[4];
#pragma unroll
  for (int j = 0; j < 4; ++j) m[j] = maskf[(size_t)g*NT + j];
  const float denom = fmaxf(m[0]+m[1]+m[2]+m[3], 1.0f);
  float c[4] = {0.f, 0.f, 0.f, 0.f};
#pragma unroll
  for (int i = 0; i < 4; ++i) {
    float x[4];
#pragma unroll
    for (int j = 0; j < 4; ++j) x[j] = (m[j] > 0.f) ? lg[i*4+j]*scale : -1e9f;
    const float mx = fmaxf(fmaxf(x[0],x[1]), fmaxf(x[2],x[3]));
    float pb[4], sum = 0.f;
#pragma unroll
    for (int j = 0; j < 4; ++j) { pb[j] = expf(x[j]-mx); sum += pb[j]; }
    const float w = m[i] / (sum * denom);
#pragma unroll
    for (int j = 0; j < 4; ++j) c[j] += pb[j] * w;
  }
  const int e0 = tid * 8;
  float f0[8], f1[8], f2[8], f3[8];
  unpack8(*reinterpret_cast<const uint4*>(F + ((size_t)g*4 + 0)*ND + e0), f0);
  unpack8(*reinterpret_cast<const uint4*>(F + ((size_t)g*4 + 1)*ND + e0), f1);
  unpack8(*reinterpret_cast<const uint4*>(F + ((size_t)g*4 + 2)*ND + e0), f2);
  unpack8(*reinterpret_cast<const uint4*>(F + ((size_t)g*4 + 3)*ND + e0), f3);
  unsigned int pk[4];
#pragma unroll
  for (int jj = 0; jj < 4; ++jj) {
    float ulo = c[0]*f0[2*jj]   + c[1]*f1[2*jj]   + c[2]*f2[2*jj]   + c[3]*f3[2*jj];
    float uhi = c[0]*f0[2*jj+1] + c[1]*f1[2*jj+1] + c[2]*f2[2*jj+1] + c[3]*f3[2*jj+1];
    pk[jj] = (unsigned int)f2bf(ulo) | ((unsigned int)f2bf(uhi) << 16);
  }
  *reinterpret_cast<uint4*>(U + (size_t)g*ND + e0) = make_uint4(pk[0],pk[1],pk[2],pk[3]);
}

// ---------- pred GEMM: 128^2, BK=32, RING-2 (32 KiB), 4 blocks/CU -------------
__global__ __launch_bounds__(256, 4) void gemm_pred_r2(
    const unsigned short* __restrict__ A, const unsigned short* __restrict__ B,
    float* __restrict__ outp /* = out+1 */, const float* __restrict__ x_start,
    float* __restrict__ lpart, int b0)
{
  constexpr int K = ND;
  constexpr int NTILE = K / 32;   // 64
  __shared__ unsigned short lds[16384];  // 32 KiB: 2 rings x (A 8K + B 8K)
  __shared__ float r2[4];
  const int tid = threadIdx.x;
  const int lane = tid & 63, wid = tid >> 6;
  const int wm = wid >> 1, wn = wid & 1;

  const int GX = (int)gridDim.x;   // 16
  const int nwg = GX * (int)gridDim.y;
  const int o = (int)blockIdx.y * GX + (int)blockIdx.x;
  const int swz = (o & 7) * (nwg >> 3) + (o >> 3);
  const int bx = swz % GX, by = swz / GX;
  const size_t arow0 = (size_t)by * 128;
  const size_t bcol0 = (size_t)bx * 128;
  char* ldsb = (char*)lds;

  const int row0 = tid >> 2, row1 = row0 + 64;
  const int kc = (((tid & 3) ^ ((tid >> 3) & 3))) * 8;
  const unsigned short* ga0 = A + (arow0 + row0) * K + kc;
  const unsigned short* ga1 = A + (arow0 + row1) * K + kc;
  const unsigned short* gb0 = B + (bcol0 + row0) * K + kc;
  const unsigned short* gb1 = B + (bcol0 + row1) * K + kc;
  const int lo0 = wid * 1024, lo1 = 4096 + wid * 1024;

#define STAGE(tt) { const int q_ = ((tt)&1)*16384; const int k_ = (tt)*32; \
    GL2LDS(ga0 + k_, ldsb + q_ + lo0);                                     \
    GL2LDS(ga1 + k_, ldsb + q_ + lo1);                                     \
    GL2LDS(gb0 + k_, ldsb + q_ + 8192 + lo0);                              \
    GL2LDS(gb1 + k_, ldsb + q_ + 8192 + lo1); }

  const int ar = (lane & 15);
  const int ko2 = ((lane >> 4) ^ ((lane >> 1) & 3)) * 16;  // bytes

  f32x4 acc[4][4] = {};

  STAGE(0);
  waitv0();
  __builtin_amdgcn_s_barrier();

  for (int t = 0; t < NTILE; ++t) {
    const char* rg = ldsb + (t & 1) * 16384;
    bf16x8 af[4], bfr[4];
#pragma unroll
    for (int mi = 0; mi < 4; ++mi)
      af[mi] = *reinterpret_cast<const bf16x8*>(rg + (wm*64 + mi*16 + ar)*64 + ko2);
#pragma unroll
    for (int ni = 0; ni < 4; ++ni)
      bfr[ni] = *reinterpret_cast<const bf16x8*>(rg + 8192 + (wn*64 + ni*16 + ar)*64 + ko2);
    if (t + 1 < NTILE) STAGE(t + 1);
    __builtin_amdgcn_s_setprio(1);
#pragma unroll
    for (int mi = 0; mi < 4; ++mi)
#pragma unroll
      for (int ni = 0; ni < 4; ++ni)
        acc[mi][ni] = __builtin_amdgcn_mfma_f32_16x16x32_bf16(af[mi], bfr[ni], acc[mi][ni], 0, 0, 0);
    __builtin_amdgcn_s_setprio(0);
    if (t + 1 < NTILE) waitv0();
    __builtin_amdgcn_s_barrier();
  }
#undef STAGE

  float sse = 0.f;
#pragma unroll
  for (int mi = 0; mi < 4; ++mi)
#pragma unroll
    for (int ni = 0; ni < 4; ++ni) {
      const size_t col = bcol0 + wn*64 + ni*16 + (lane & 15);
#pragma unroll
      for (int r = 0; r < 4; ++r) {
        const size_t row = arow0 + wm*64 + mi*16 + (lane >> 4)*4 + r;  // chunk-local b
        const size_t gb  = (size_t)b0 + row;                           // global b
        const float p = acc[mi][ni][r];
        outp[gb * ND + col] = p;
        const float d = p - x_start[gb * ND + col];
        sse += d * d;
      }
    }
#pragma unroll
  for (int o2 = 32; o2 > 0; o2 >>= 1) sse += __shfl_xor(sse, o2);
  if (lane == 0) r2[wid] = sse;
  __syncthreads();
  if (tid == 0) {
    const int slot = ((b0 >> 7) + by) * 16 + bx;
    lpart[slot] = r2[0] + r2[1] + r2[2] + r2[3];
  }
}

// ---------- deterministic loss reduce (1024 fixed slots) ----------------------
__global__ __launch_bounds__(256) void loss_final(const float* __restrict__ lpart,
                                                  float* __restrict__ out) {
  const int tid = threadIdx.x;
  float s = 0.f;
  for (int i = tid; i < 1024; i += 256) s += lpart[i];
#pragma unroll
  for (int o = 32; o > 0; o >>= 1) s += __shfl_xor(s, o);
  __shared__ float red[4];
  const int lane = tid & 63, wid = tid >> 6;
  if (lane == 0) red[wid] = s;
  __syncthreads();
  if (tid == 0) out[0] = (red[0]+red[1]+red[2]+red[3]) * (1.0f / 16777216.0f);
}

extern "C" void kernel_launch(void* const* d_in, const int* in_sizes, int n_in,
                              void* d_out, int out_size, void* d_ws, size_t ws_size,
                              hipStream_t stream) {
  const float* x_start   = (const float*)d_in[0];
  const int*   tarr      = (const int*)  d_in[1];
  const float* noise     = (const float*)d_in[2];
  const float* cond_src  = (const float*)d_in[3];
  const float* cond_tgt  = (const float*)d_in[4];
  const float* w_q       = (const float*)d_in[5];
  const float* w_k       = (const float*)d_in[6];
  const float* w_v       = (const float*)d_in[7];
  const float* sqrt_ac   = (const float*)d_in[8];
  const float* sqrt_omac = (const float*)d_in[9];
  float* out = (float*)d_out;
  char*  ws  = (char*)d_ws;

  // CB capped at 4096 (whole-batch path showed L2-locality loss, r10)
  size_t CB;
  if      (ws_size >= 151064576ull) CB = 4096;
  else if (ws_size >=  83922944ull) CB = 2048;
  else if (ws_size >=  50352128ull) CB = 1024;
  else return;

  const size_t offG  = 0;                        //  8 MiB
  const size_t offWv = 8388608;                  //  8 MiB
  const size_t offF  = 16777216;                 //  CB*16384
  const size_t szF   = CB * 16384;
  const size_t offU  = offF + szF;               //  CB*4096 (U, dense)
  const size_t offPl = offU + CB * 4096;         //  CB*2048 (32x16 f32 per group)
  const size_t offMask = offPl + CB * 2048;
  const size_t offLp   = offMask + CB * 16;

  unsigned short* G    = (unsigned short*)(ws + offG);
  unsigned short* WvBf = (unsigned short*)(ws + offWv);
  unsigned short* F    = (unsigned short*)(ws + offF);
  unsigned short* U    = (unsigned short*)(ws + offU);
  float* plog  = (float*)(ws + offPl);
  float* maskC = (float*)(ws + offMask);
  float* lpart = (float*)(ws + offLp);
  unsigned short* WqT = F;
  unsigned short* WkT = U;   // dead before u_from_logits writes U

  prep_weights<<<dim3(32, 32, 3), 256, 0, stream>>>(w_q, w_k, w_v, WqT, WkT, WvBf);
  gemm_nt_bf16<<<dim3(16, 16), 256, 0, stream>>>(WqT, WkT, G);   // G = Wq^T Wk

  const int nchunks = NB / (int)CB;
  for (int ci = 0; ci < nchunks; ++ci) {
    const int b0 = ci * (int)CB;
    prep_tokens<<<dim3(NT, (int)CB), 256, 0, stream>>>(
        x_start, tarr, noise, cond_src, cond_tgt, sqrt_ac, sqrt_omac, F, maskC, b0);
    gemm_nt_256<<<dim3(ND/256, (NT*(int)CB)/256), 512, 0, stream>>>(
        F, G, plog, (int)CB);                                       // H-GEMM + logits
    u_from_logits<<<dim3((int)CB), 256, 0, stream>>>(F, plog, maskC, U);
    gemm_pred_r2<<<dim3(16, (int)CB / 128), 256, 0, stream>>>(
        U, WvBf, out + 1, x_start, lpart, b0);                      // pred = U Wv^T
  }
  loss_final<<<dim3(1), 256, 0, stream>>>(lpart, out);
}